// Round 7
// baseline (1818.112 us; speedup 1.0000x reference)
//
#include <hip/hip_runtime.h>

#define PTS 8192          // B*N = 4*2048 points
#define HDIM 512
#define BN_EPS 1e-4f
#define HSTR 520          // LDS row stride (elems); b128 reads land 2-way only (free)

typedef unsigned short u16;
typedef u16 u16x8 __attribute__((ext_vector_type(8)));
typedef short s16x8 __attribute__((ext_vector_type(8)));
typedef float f32x4 __attribute__((ext_vector_type(4)));

__device__ __forceinline__ float bf2f(u16 u) {
  unsigned x = ((unsigned)u) << 16;
  return __builtin_bit_cast(float, x);
}
__device__ __forceinline__ u16 f2bf(float f) {
  unsigned x = __builtin_bit_cast(unsigned, f);
  x += 0x7fffu + ((x >> 16) & 1u);
  return (u16)(x >> 16);
}
__device__ __forceinline__ float sigf(float x) {
  return __builtin_amdgcn_rcpf(1.f + __expf(-x));
}
__device__ __forceinline__ float fast_tanh(float x) {
  float e = __expf(2.f * x);
  return 1.f - 2.f * __builtin_amdgcn_rcpf(e + 1.f);
}
__device__ __forceinline__ void gl2lds16(const u16* g, u16* l) {
  __builtin_amdgcn_global_load_lds(
      (const __attribute__((address_space(1))) void*)g,
      (__attribute__((address_space(3))) void*)l, 16, 0, 0);
}

// ---------------------------------------------------------------- prep
struct PrepArgs {
  const float *W1, *W2;
  u16 *W1b, *W2b;
  const float* c;
  u16* cb;
  const float *Wg0, *Wg1, *Wg2, *Wb0, *Wb1, *Wb2;
  const float *bg0, *bg1, *bg2;
  u16* Wpack;          // [6*512][64] bf16
  float* bias_pack;    // [3072]
  const float *x, *m1, *v1, *lg1, *be1;
  float *x_cur, *lp_state;
  const float *Wg3, *bg3, *Wb3;
  float *G3, *B3;
};
__global__ void prep_kernel(PrepArgs a) {
  int i = blockIdx.x * 256 + threadIdx.x;   // 0 .. 524287
  if (i < 512 * 512) { a.W1b[i] = f2bf(a.W1[i]); a.W2b[i] = f2bf(a.W2[i]); }
  if (i < PTS * 64) a.cb[i] = f2bf(a.c[i]);
  if (i < 6 * 512 * 64) {
    int sec = i >> 15;
    int within = i & 32767;
    int o = within >> 6, k = within & 63;
    const float* src[6] = {a.Wg0, a.Wg1, a.Wg2, a.Wb0, a.Wb1, a.Wb2};
    a.Wpack[i] = f2bf(src[sec][o * 65 + 1 + k]);
  }
  if (i < 3072) {
    int sec = i >> 9, o = i & 511;
    const float* bgl[3] = {a.bg0, a.bg1, a.bg2};
    a.bias_pack[i] = (sec < 3) ? bgl[sec][o] : 0.f;
  }
  if (i < PTS * 3) {
    int d = i % 3;
    a.x_cur[i] = (a.x[i] - a.m1[d]) * __expf(a.lg1[d]) * rsqrtf(a.v1[d] + BN_EPS) + a.be1[d];
  }
  if (i < PTS) a.lp_state[i] = 0.f;
  {
    int lane = threadIdx.x & 63;
    int p = (blockIdx.x * 256 + threadIdx.x) >> 6;   // 0..8191
    float cv = a.c[(size_t)p * 64 + lane];
    float ag[3], ab[3];
    #pragma unroll
    for (int o = 0; o < 3; ++o) {
      ag[o] = cv * a.Wg3[o * 65 + 1 + lane];
      ab[o] = cv * a.Wb3[o * 65 + 1 + lane];
    }
    #pragma unroll
    for (int off = 32; off > 0; off >>= 1) {
      #pragma unroll
      for (int o = 0; o < 3; ++o) {
        ag[o] += __shfl_xor(ag[o], off);
        ab[o] += __shfl_xor(ab[o], off);
      }
    }
    if (lane == 0) {
      #pragma unroll
      for (int o = 0; o < 3; ++o) {
        a.G3[p * 3 + o] = ag[o] + a.bg3[o];
        a.B3[p * 3 + o] = ab[o];
      }
    }
  }
}

// ---------------------------------------------------------------- gates GEMM (proven)
struct GatesGemmArgs {
  const u16 *A, *W;
  const float* bias;
  u16* GB;                 // [6][8192][512]
};
__global__ __launch_bounds__(256) void gates_gemm(GatesGemmArgs a) {
  __shared__ u16 As[128 * 32];
  __shared__ u16 Bs[128 * 32];
  int tid = threadIdx.x;
  int m0 = blockIdx.x * 128, n0 = blockIdx.y * 128;
  int wave = tid >> 6, lane = tid & 63;
  int wm = (wave & 1) * 64, wn = (wave >> 1) * 64;
  int lr = lane & 15, quad = lane >> 4;

  int rowS = tid >> 2, colS = (tid & 3) * 8;
  const u16* gA0 = a.A + (size_t)(m0 + rowS) * 64 + colS;
  const u16* gB0 = a.W + (size_t)(n0 + rowS) * 64 + colS;
  u16* sA0 = &As[tid * 8];
  u16* sA1 = &As[2048 + tid * 8];
  u16* sB0 = &Bs[tid * 8];
  u16* sB1 = &Bs[2048 + tid * 8];

  f32x4 acc[4][4];
  #pragma unroll
  for (int i = 0; i < 4; ++i)
    #pragma unroll
    for (int j = 0; j < 4; ++j)
      #pragma unroll
      for (int r = 0; r < 4; ++r) acc[i][j][r] = 0.f;

  for (int k0 = 0; k0 < 64; k0 += 32) {
    if (k0) __syncthreads();
    gl2lds16(gA0 + k0, sA0);
    gl2lds16(gA0 + (size_t)64 * 64 + k0, sA1);
    gl2lds16(gB0 + k0, sB0);
    gl2lds16(gB0 + (size_t)64 * 64 + k0, sB1);
    __syncthreads();
    s16x8 af[4], bfr[4];
    #pragma unroll
    for (int i = 0; i < 4; ++i)
      af[i] = *(const s16x8*)&As[(wm + i * 16 + lr) * 32 + quad * 8];
    #pragma unroll
    for (int j = 0; j < 4; ++j)
      bfr[j] = *(const s16x8*)&Bs[(wn + j * 16 + lr) * 32 + quad * 8];
    #pragma unroll
    for (int i = 0; i < 4; ++i)
      #pragma unroll
      for (int j = 0; j < 4; ++j)
        acc[i][j] = __builtin_amdgcn_mfma_f32_16x16x32_bf16(af[i], bfr[j], acc[i][j], 0, 0, 0);
  }

  #pragma unroll
  for (int j = 0; j < 4; ++j) {
    int n = n0 + wn + j * 16 + lr;
    int sec = n >> 9, col = n & 511;
    float bv = a.bias[n];
    u16* outp = a.GB + (size_t)sec * PTS * 512 + col;
    #pragma unroll
    for (int i = 0; i < 4; ++i) {
      int mrow = m0 + wm + i * 16 + quad * 4;
      #pragma unroll
      for (int r = 0; r < 4; ++r)
        outp[(size_t)(mrow + r) * 512] = f2bf(acc[i][j][r] + bv);
    }
  }
}

// ---------------------------------------------------------------- persistent flow kernel
// 512 blocks x 512 threads; block owns 16 points for the ENTIRE 12-stage RK4.
// Per-point state (x, kx, kl, lp, accum6) lives in LDS; no cross-point coupling.
// Wave w covers n-slice [w*64, w*64+64) and all 64 m-rows (16 pts x 4 streams).
struct RunArgs {
  const float* sqrtT;
  const u16 *G0, *Bc0, *G1, *Bc1, *G2, *Bc2;
  const float *G3, *B3;
  const float *W0, *b0, *Wg0, *Wb0;
  const u16* W1b; const float *b1, *Wg1, *Wb1;
  const u16* W2b; const float *b2, *Wg2, *Wb2;
  const float *W3, *b3, *Wg3, *Wb3;
  const float* x0;            // post-BN1 initial x
  float* out_x;
  float* lp_state;
  const float *m2, *v2, *lg2, *be2;
};

__global__ __launch_bounds__(512, 4) void flow_kernel(RunArgs a) {
  __shared__ __align__(16) u16 Hs[64 * HSTR];   // 66.6 KB
  __shared__ float xb[16][3], xv[16][3], kxs[16][3];
  __shared__ float kls[16], lps[16];
  __shared__ float part[8][16][6];
  __shared__ float acc6[16][6];
  int tid = threadIdx.x;
  int w = tid >> 6, lane = tid & 63, lr = lane & 15, quad = lane >> 4;
  int n0 = w * 64;
  int p0 = blockIdx.x * 16;
  float s0v = a.sqrtT[0];
  float dt = s0v * s0v * (1.f / 3.f);

  if (tid < 16) {
    int p = p0 + tid;
    xb[tid][0] = a.x0[p * 3]; xb[tid][1] = a.x0[p * 3 + 1]; xb[tid][2] = a.x0[p * 3 + 2];
    xv[tid][0] = xb[tid][0];  xv[tid][1] = xb[tid][1];      xv[tid][2] = xb[tid][2];
    kxs[tid][0] = kxs[tid][1] = kxs[tid][2] = 0.f;
    kls[tid] = 0.f; lps[tid] = 0.f;
  }
  __syncthreads();

  #pragma unroll 1
  for (int s = 0; s < 12; ++s) {
    int sm = s & 3;
    float ts = (float)(s >> 2) + (sm == 0 ? 0.f : (sm == 3 ? 1.f : 0.5f));

    // ---- fold previous stage's accum into RK4 state (thread per point)
    if (s > 0) {
      if (tid < 16) {
        int p = p0 + tid;
        int pm = (s - 1) & 3;
        float tsp = (float)((s - 1) >> 2) + (pm == 0 ? 0.f : (pm == 3 ? 1.f : 0.5f));
        float tp = tsp * dt;
        float dx[3], gate[3];
        #pragma unroll
        for (int r = 0; r < 3; ++r) {
          gate[r] = sigf(a.G3[p * 3 + r] + tp * a.Wg3[r * 65]);
          float bias = a.B3[p * 3 + r] + tp * a.Wb3[r * 65];
          dx[r] = fmaf(acc6[tid][r] + a.b3[r], gate[r], bias);
        }
        float klv = -(acc6[tid][3] * gate[0] + acc6[tid][4] * gate[1] + acc6[tid][5] * gate[2]);
        if (pm == 0) {
          #pragma unroll
          for (int r = 0; r < 3; ++r) {
            kxs[tid][r] = dx[r];
            xv[tid][r] = xb[tid][r] + 0.5f * dt * dx[r];
          }
          kls[tid] = klv;
        } else if (pm == 1) {
          #pragma unroll
          for (int r = 0; r < 3; ++r) {
            kxs[tid][r] += 2.f * dx[r];
            xv[tid][r] = xb[tid][r] + 0.5f * dt * dx[r];
          }
          kls[tid] += 2.f * klv;
        } else if (pm == 2) {
          #pragma unroll
          for (int r = 0; r < 3; ++r) {
            kxs[tid][r] += 2.f * dx[r];
            xv[tid][r] = xb[tid][r] + dt * dx[r];
          }
          kls[tid] += 2.f * klv;
        } else {
          float sc = dt * (1.f / 6.f);
          #pragma unroll
          for (int r = 0; r < 3; ++r) {
            xb[tid][r] += sc * (kxs[tid][r] + dx[r]);
            xv[tid][r] = xb[tid][r];
          }
          lps[tid] += sc * (kls[tid] + klv);
        }
      }
      __syncthreads();
    }

    float t = ts * dt;

    // ---- layer0: 32 threads per point, 16 cols each -> H1 in LDS
    {
      int pl = tid >> 5, p = p0 + pl;
      float x0 = xv[pl][0], x1 = xv[pl][1], x2 = xv[pl][2];
      int base_o = (tid & 31) * 16;
      #pragma unroll
      for (int cc = 0; cc < 2; ++cc) {
        int ob = base_o + cc * 8;
        u16x8 g8 = *(const u16x8*)(a.G0 + (size_t)p * 512 + ob);
        u16x8 c8 = *(const u16x8*)(a.Bc0 + (size_t)p * 512 + ob);
        u16x8 oh, od0, od1, od2;
        #pragma unroll
        for (int jj = 0; jj < 8; ++jj) {
          int o = ob + jj;
          float w0 = a.W0[o * 3], w1 = a.W0[o * 3 + 1], w2 = a.W0[o * 3 + 2];
          float u = fmaf(w0, x0, fmaf(w1, x1, w2 * x2)) + a.b0[o];
          float gate = sigf(bf2f(g8[jj]) + t * a.Wg0[o * 65]);
          float bias = bf2f(c8[jj]) + t * a.Wb0[o * 65];
          float z = fmaf(u, gate, bias);
          float h = fast_tanh(z);
          float wm = (1.f - h * h) * gate;
          oh[jj] = f2bf(h);
          od0[jj] = f2bf(wm * w0);
          od1[jj] = f2bf(wm * w1);
          od2[jj] = f2bf(wm * w2);
        }
        size_t hb = (size_t)(pl * 4) * HSTR + ob;
        *(u16x8*)(Hs + hb) = oh;
        *(u16x8*)(Hs + hb + HSTR) = od0;
        *(u16x8*)(Hs + hb + 2 * HSTR) = od1;
        *(u16x8*)(Hs + hb + 3 * HSTR) = od2;
      }
    }
    __syncthreads();

    // ---- layer1 GEMM (64x64 per wave; all loops indexing acc fully unrolled)
    f32x4 acc[4][4];
    #pragma unroll
    for (int i = 0; i < 4; ++i)
      #pragma unroll
      for (int j = 0; j < 4; ++j)
        #pragma unroll
        for (int r = 0; r < 4; ++r) acc[i][j][r] = 0.f;
    {
      const u16* wp = a.W1b + ((size_t)(n0 + lr) * 512 + quad * 8);
      #pragma unroll 1
      for (int k0 = 0; k0 < 512; k0 += 32) {
        s16x8 bf[4], af[4];
        #pragma unroll
        for (int j = 0; j < 4; ++j)
          bf[j] = *(const s16x8*)(wp + (size_t)j * 16 * 512 + k0);
        #pragma unroll
        for (int i = 0; i < 4; ++i)
          af[i] = *(const s16x8*)(Hs + (i * 16 + lr) * HSTR + k0 + quad * 8);
        #pragma unroll
        for (int i = 0; i < 4; ++i)
          #pragma unroll
          for (int j = 0; j < 4; ++j)
            acc[i][j] = __builtin_amdgcn_mfma_f32_16x16x32_bf16(af[i], bf[j], acc[i][j], 0, 0, 0);
      }
    }
    __syncthreads();   // all H1 reads done

    // ---- epilogue1 -> H2 in same LDS
    #pragma unroll
    for (int j = 0; j < 4; ++j) {
      int n = n0 + j * 16 + lr;
      float bvn = a.b1[n];
      float wg0 = a.Wg1[n * 65], wb0 = a.Wb1[n * 65];
      #pragma unroll
      for (int i = 0; i < 4; ++i) {
        int p = p0 + i * 4 + quad;
        float gate = sigf(bf2f(a.G1[(size_t)p * 512 + n]) + t * wg0);
        float bias = bf2f(a.Bc1[(size_t)p * 512 + n]) + t * wb0;
        f32x4 u = acc[i][j];
        float z = fmaf(u[0] + bvn, gate, bias);
        float h = fast_tanh(z);
        float wmf = (1.f - h * h) * gate;
        int row = i * 16 + quad * 4;
        Hs[(size_t)row * HSTR + n] = f2bf(h);
        Hs[(size_t)(row + 1) * HSTR + n] = f2bf(u[1] * wmf);
        Hs[(size_t)(row + 2) * HSTR + n] = f2bf(u[2] * wmf);
        Hs[(size_t)(row + 3) * HSTR + n] = f2bf(u[3] * wmf);
      }
    }
    __syncthreads();

    // ---- layer2 GEMM
    #pragma unroll
    for (int i = 0; i < 4; ++i)
      #pragma unroll
      for (int j = 0; j < 4; ++j)
        #pragma unroll
        for (int r = 0; r < 4; ++r) acc[i][j][r] = 0.f;
    {
      const u16* wp = a.W2b + ((size_t)(n0 + lr) * 512 + quad * 8);
      #pragma unroll 1
      for (int k0 = 0; k0 < 512; k0 += 32) {
        s16x8 bf[4], af[4];
        #pragma unroll
        for (int j = 0; j < 4; ++j)
          bf[j] = *(const s16x8*)(wp + (size_t)j * 16 * 512 + k0);
        #pragma unroll
        for (int i = 0; i < 4; ++i)
          af[i] = *(const s16x8*)(Hs + (i * 16 + lr) * HSTR + k0 + quad * 8);
        #pragma unroll
        for (int i = 0; i < 4; ++i)
          #pragma unroll
          for (int j = 0; j < 4; ++j)
            acc[i][j] = __builtin_amdgcn_mfma_f32_16x16x32_bf16(af[i], bf[j], acc[i][j], 0, 0, 0);
      }
    }

    // ---- epilogue2: gate/tanh + project onto W3 -> 6 partials per point
    #pragma unroll
    for (int i = 0; i < 4; ++i) {
      float v0 = 0.f, v1 = 0.f, v2 = 0.f, v3 = 0.f, v4 = 0.f, v5 = 0.f;
      int pl = i * 4 + quad;
      int p = p0 + pl;
      #pragma unroll
      for (int j = 0; j < 4; ++j) {
        int n = n0 + j * 16 + lr;
        float bvn = a.b2[n];
        float wg0 = a.Wg2[n * 65], wb0 = a.Wb2[n * 65];
        float gate = sigf(bf2f(a.G2[(size_t)p * 512 + n]) + t * wg0);
        float bias = bf2f(a.Bc2[(size_t)p * 512 + n]) + t * wb0;
        f32x4 u = acc[i][j];
        float z = fmaf(u[0] + bvn, gate, bias);
        float h = fast_tanh(z);
        float wmf = (1.f - h * h) * gate;
        float w30 = a.W3[n], w31 = a.W3[512 + n], w32 = a.W3[1024 + n];
        v0 = fmaf(h, w30, v0);
        v1 = fmaf(h, w31, v1);
        v2 = fmaf(h, w32, v2);
        v3 = fmaf(u[1] * wmf, w30, v3);
        v4 = fmaf(u[2] * wmf, w31, v4);
        v5 = fmaf(u[3] * wmf, w32, v5);
      }
      #pragma unroll
      for (int mask = 1; mask <= 8; mask <<= 1) {
        v0 += __shfl_xor(v0, mask);
        v1 += __shfl_xor(v1, mask);
        v2 += __shfl_xor(v2, mask);
        v3 += __shfl_xor(v3, mask);
        v4 += __shfl_xor(v4, mask);
        v5 += __shfl_xor(v5, mask);
      }
      float val = (lr == 0) ? v0 : (lr == 1) ? v1 : (lr == 2) ? v2
                : (lr == 3) ? v3 : (lr == 4) ? v4 : v5;
      if (lr < 6) part[w][pl][lr] = val;
    }
    __syncthreads();

    if (tid < 96) {
      int pt = tid / 6, d = tid - pt * 6;
      float sum = 0.f;
      #pragma unroll
      for (int ww = 0; ww < 8; ++ww) sum += part[ww][pt][d];
      acc6[pt][d] = sum;
    }
    __syncthreads();
  }

  // ---- final fold (mode 3, ts_prev = 3.0) + BN2 + outputs
  if (tid < 16) {
    int p = p0 + tid;
    float tp = 3.f * dt;
    float dx[3], gate[3];
    #pragma unroll
    for (int r = 0; r < 3; ++r) {
      gate[r] = sigf(a.G3[p * 3 + r] + tp * a.Wg3[r * 65]);
      float bias = a.B3[p * 3 + r] + tp * a.Wb3[r * 65];
      dx[r] = fmaf(acc6[tid][r] + a.b3[r], gate[r], bias);
    }
    float klv = -(acc6[tid][3] * gate[0] + acc6[tid][4] * gate[1] + acc6[tid][5] * gate[2]);
    float sc = dt * (1.f / 6.f);
    #pragma unroll
    for (int r = 0; r < 3; ++r) {
      float xf = xb[tid][r] + sc * (kxs[tid][r] + dx[r]);
      a.out_x[p * 3 + r] = (xf - a.m2[r]) * __expf(a.lg2[r]) * rsqrtf(a.v2[r] + BN_EPS) + a.be2[r];
    }
    a.lp_state[p] = lps[tid] + sc * (kls[tid] + klv);
  }
}

// ---------------------------------------------------------------- finish lp
__global__ void finish_lp(const float* __restrict__ lp_state,
                          const float* __restrict__ v1, const float* __restrict__ lg1,
                          const float* __restrict__ v2, const float* __restrict__ lg2,
                          float* __restrict__ out) {
  int b = blockIdx.x, tid = threadIdx.x;
  float s = 0.f;
  for (int n = tid; n < 2048; n += 256) s += lp_state[b * 2048 + n];
  __shared__ float red[256];
  red[tid] = s;
  __syncthreads();
  for (int w = 128; w > 0; w >>= 1) {
    if (tid < w) red[tid] += red[tid + w];
    __syncthreads();
  }
  if (tid == 0) {
    float ld = 0.f;
    for (int d = 0; d < 3; ++d) {
      ld += lg1[d] - 0.5f * logf(v1[d] + BN_EPS);
      ld += lg2[d] - 0.5f * logf(v2[d] + BN_EPS);
    }
    out[b] = red[0] - 2048.f * ld;
  }
}

// ---------------------------------------------------------------- launch
extern "C" void kernel_launch(void* const* d_in, const int* in_sizes, int n_in,
                              void* d_out, int out_size, void* d_ws, size_t ws_size,
                              hipStream_t stream) {
  const float* x        = (const float*)d_in[0];
  const float* c        = (const float*)d_in[1];
  const float* bn1_mean = (const float*)d_in[2];
  const float* bn1_var  = (const float*)d_in[3];
  const float* bn1_lg   = (const float*)d_in[4];
  const float* bn1_beta = (const float*)d_in[5];
  const float* bn2_mean = (const float*)d_in[6];
  const float* bn2_var  = (const float*)d_in[7];
  const float* bn2_lg   = (const float*)d_in[8];
  const float* bn2_beta = (const float*)d_in[9];
  const float* sqrtT    = (const float*)d_in[10];
  const float* W0  = (const float*)d_in[11];
  const float* b0  = (const float*)d_in[12];
  const float* Wg0 = (const float*)d_in[13];
  const float* bg0 = (const float*)d_in[14];
  const float* Wb0 = (const float*)d_in[15];
  const float* W1  = (const float*)d_in[16];
  const float* b1  = (const float*)d_in[17];
  const float* Wg1 = (const float*)d_in[18];
  const float* bg1 = (const float*)d_in[19];
  const float* Wb1 = (const float*)d_in[20];
  const float* W2  = (const float*)d_in[21];
  const float* b2  = (const float*)d_in[22];
  const float* Wg2 = (const float*)d_in[23];
  const float* bg2 = (const float*)d_in[24];
  const float* Wb2 = (const float*)d_in[25];
  const float* W3  = (const float*)d_in[26];
  const float* b3  = (const float*)d_in[27];
  const float* Wg3 = (const float*)d_in[28];
  const float* bg3 = (const float*)d_in[29];
  const float* Wb3 = (const float*)d_in[30];

  char* base = (char*)d_ws;
  size_t off = 0;
  auto alloc = [&](size_t bytes) -> void* {
    void* pp = base + off;
    off += (bytes + 255) & ~(size_t)255;
    return pp;
  };
  u16* W1b = (u16*)alloc((size_t)512 * 512 * 2);
  u16* W2b = (u16*)alloc((size_t)512 * 512 * 2);
  u16* cb  = (u16*)alloc((size_t)PTS * 64 * 2);
  u16* Wpack = (u16*)alloc((size_t)6 * 512 * 64 * 2);
  float* bias_pack = (float*)alloc((size_t)3072 * 4);
  u16* GB = (u16*)alloc((size_t)6 * PTS * 512 * 2);
  const size_t SZ = (size_t)PTS * 512;
  u16* G0p  = GB;           u16* G1p = GB + SZ;      u16* G2p = GB + 2 * SZ;
  u16* Bc0p = GB + 3 * SZ;  u16* Bc1p = GB + 4 * SZ; u16* Bc2p = GB + 5 * SZ;
  float* G3f = (float*)alloc((size_t)PTS * 3 * 4);
  float* B3f = (float*)alloc((size_t)PTS * 3 * 4);
  float* x_cur    = (float*)alloc((size_t)PTS * 3 * 4);
  float* lp_state = (float*)alloc((size_t)PTS * 4);
  (void)ws_size; (void)in_sizes; (void)n_in; (void)out_size;

  PrepArgs pa{W1, W2, W1b, W2b, c, cb, Wg0, Wg1, Wg2, Wb0, Wb1, Wb2,
              bg0, bg1, bg2, Wpack, bias_pack, x, bn1_mean, bn1_var,
              bn1_lg, bn1_beta, x_cur, lp_state, Wg3, bg3, Wb3, G3f, B3f};
  prep_kernel<<<2048, 256, 0, stream>>>(pa);

  GatesGemmArgs gg{cb, Wpack, bias_pack, GB};
  gates_gemm<<<dim3(64, 24), 256, 0, stream>>>(gg);

  RunArgs ra{sqrtT, G0p, Bc0p, G1p, Bc1p, G2p, Bc2p, G3f, B3f,
             W0, b0, Wg0, Wb0,
             W1b, b1, Wg1, Wb1,
             W2b, b2, Wg2, Wb2,
             W3, b3, Wg3, Wb3,
             x_cur, (float*)d_out, lp_state,
             bn2_mean, bn2_var, bn2_lg, bn2_beta};
  flow_kernel<<<PTS / 16, 512, 0, stream>>>(ra);

  finish_lp<<<4, 256, 0, stream>>>(lp_state, bn1_var, bn1_lg, bn2_var, bn2_lg,
                                   (float*)d_out + PTS * 3);
}

// Round 8
// 1254.306 us; speedup vs baseline: 1.4495x; 1.4495x over previous
//
#include <hip/hip_runtime.h>

#define PTS 8192          // B*N = 4*2048 points
#define HDIM 512
#define BN_EPS 1e-4f
#define HSTR 520          // LDS row stride (elems); b128 reads land 2-way only (free)

typedef unsigned short u16;
typedef u16 u16x8 __attribute__((ext_vector_type(8)));
typedef short s16x8 __attribute__((ext_vector_type(8)));
typedef float f32x4 __attribute__((ext_vector_type(4)));

__device__ __forceinline__ float bf2f(u16 u) {
  unsigned x = ((unsigned)u) << 16;
  return __builtin_bit_cast(float, x);
}
__device__ __forceinline__ u16 f2bf(float f) {
  unsigned x = __builtin_bit_cast(unsigned, f);
  x += 0x7fffu + ((x >> 16) & 1u);
  return (u16)(x >> 16);
}
__device__ __forceinline__ float sigf(float x) {
  return __builtin_amdgcn_rcpf(1.f + __expf(-x));
}
__device__ __forceinline__ float fast_tanh(float x) {
  float e = __expf(2.f * x);
  return 1.f - 2.f * __builtin_amdgcn_rcpf(e + 1.f);
}
__device__ __forceinline__ void gl2lds16(const u16* g, u16* l) {
  __builtin_amdgcn_global_load_lds(
      (const __attribute__((address_space(1))) void*)g,
      (__attribute__((address_space(3))) void*)l, 16, 0, 0);
}

// ---------------------------------------------------------------- prep
struct PrepArgs {
  const float *W1, *W2;
  u16 *W1b, *W2b;
  const float* c;
  u16* cb;
  const float *Wg0, *Wg1, *Wg2, *Wb0, *Wb1, *Wb2;
  const float *bg0, *bg1, *bg2;
  u16* Wpack;          // [6*512][64] bf16
  float* bias_pack;    // [3072]
  const float *x, *m1, *v1, *lg1, *be1;
  float *x_cur, *lp_state;
  const float *Wg3, *bg3, *Wb3;
  float *G3, *B3;
};
__global__ void prep_kernel(PrepArgs a) {
  int i = blockIdx.x * 256 + threadIdx.x;   // 0 .. 524287
  if (i < 512 * 512) { a.W1b[i] = f2bf(a.W1[i]); a.W2b[i] = f2bf(a.W2[i]); }
  if (i < PTS * 64) a.cb[i] = f2bf(a.c[i]);
  if (i < 6 * 512 * 64) {
    int sec = i >> 15;
    int within = i & 32767;
    int o = within >> 6, k = within & 63;
    const float* src[6] = {a.Wg0, a.Wg1, a.Wg2, a.Wb0, a.Wb1, a.Wb2};
    a.Wpack[i] = f2bf(src[sec][o * 65 + 1 + k]);
  }
  if (i < 3072) {
    int sec = i >> 9, o = i & 511;
    const float* bgl[3] = {a.bg0, a.bg1, a.bg2};
    a.bias_pack[i] = (sec < 3) ? bgl[sec][o] : 0.f;
  }
  if (i < PTS * 3) {
    int d = i % 3;
    a.x_cur[i] = (a.x[i] - a.m1[d]) * __expf(a.lg1[d]) * rsqrtf(a.v1[d] + BN_EPS) + a.be1[d];
  }
  if (i < PTS) a.lp_state[i] = 0.f;
  {
    int lane = threadIdx.x & 63;
    int p = (blockIdx.x * 256 + threadIdx.x) >> 6;   // 0..8191
    float cv = a.c[(size_t)p * 64 + lane];
    float ag[3], ab[3];
    #pragma unroll
    for (int o = 0; o < 3; ++o) {
      ag[o] = cv * a.Wg3[o * 65 + 1 + lane];
      ab[o] = cv * a.Wb3[o * 65 + 1 + lane];
    }
    #pragma unroll
    for (int off = 32; off > 0; off >>= 1) {
      #pragma unroll
      for (int o = 0; o < 3; ++o) {
        ag[o] += __shfl_xor(ag[o], off);
        ab[o] += __shfl_xor(ab[o], off);
      }
    }
    if (lane == 0) {
      #pragma unroll
      for (int o = 0; o < 3; ++o) {
        a.G3[p * 3 + o] = ag[o] + a.bg3[o];
        a.B3[p * 3 + o] = ab[o];
      }
    }
  }
}

// ---------------------------------------------------------------- gates GEMM (proven)
struct GatesGemmArgs {
  const u16 *A, *W;
  const float* bias;
  u16* GB;                 // [6][8192][512]
};
__global__ __launch_bounds__(256) void gates_gemm(GatesGemmArgs a) {
  __shared__ u16 As[128 * 32];
  __shared__ u16 Bs[128 * 32];
  int tid = threadIdx.x;
  int m0 = blockIdx.x * 128, n0 = blockIdx.y * 128;
  int wave = tid >> 6, lane = tid & 63;
  int wm = (wave & 1) * 64, wn = (wave >> 1) * 64;
  int lr = lane & 15, quad = lane >> 4;

  int rowS = tid >> 2, colS = (tid & 3) * 8;
  const u16* gA0 = a.A + (size_t)(m0 + rowS) * 64 + colS;
  const u16* gB0 = a.W + (size_t)(n0 + rowS) * 64 + colS;
  u16* sA0 = &As[tid * 8];
  u16* sA1 = &As[2048 + tid * 8];
  u16* sB0 = &Bs[tid * 8];
  u16* sB1 = &Bs[2048 + tid * 8];

  f32x4 acc[4][4];
  #pragma unroll
  for (int i = 0; i < 4; ++i)
    #pragma unroll
    for (int j = 0; j < 4; ++j)
      #pragma unroll
      for (int r = 0; r < 4; ++r) acc[i][j][r] = 0.f;

  for (int k0 = 0; k0 < 64; k0 += 32) {
    if (k0) __syncthreads();
    gl2lds16(gA0 + k0, sA0);
    gl2lds16(gA0 + (size_t)64 * 64 + k0, sA1);
    gl2lds16(gB0 + k0, sB0);
    gl2lds16(gB0 + (size_t)64 * 64 + k0, sB1);
    __syncthreads();
    s16x8 af[4], bfr[4];
    #pragma unroll
    for (int i = 0; i < 4; ++i)
      af[i] = *(const s16x8*)&As[(wm + i * 16 + lr) * 32 + quad * 8];
    #pragma unroll
    for (int j = 0; j < 4; ++j)
      bfr[j] = *(const s16x8*)&Bs[(wn + j * 16 + lr) * 32 + quad * 8];
    #pragma unroll
    for (int i = 0; i < 4; ++i)
      #pragma unroll
      for (int j = 0; j < 4; ++j)
        acc[i][j] = __builtin_amdgcn_mfma_f32_16x16x32_bf16(af[i], bfr[j], acc[i][j], 0, 0, 0);
  }

  #pragma unroll
  for (int j = 0; j < 4; ++j) {
    int n = n0 + wn + j * 16 + lr;
    int sec = n >> 9, col = n & 511;
    float bv = a.bias[n];
    u16* outp = a.GB + (size_t)sec * PTS * 512 + col;
    #pragma unroll
    for (int i = 0; i < 4; ++i) {
      int mrow = m0 + wm + i * 16 + quad * 4;
      #pragma unroll
      for (int r = 0; r < 4; ++r)
        outp[(size_t)(mrow + r) * 512] = f2bf(acc[i][j][r] + bv);
    }
  }
}

// ---------------------------------------------------------------- per-stage kernel
// 512 blocks x 512 threads (8 waves); block owns 16 points (64 m-rows).
// LDS ~70 KB -> 2 blocks/CU: independent blocks overlap each other's
// latency phases. Wave w owns n-slice [w*64, w*64+64), all 64 m-rows.
// All loops indexing acc are FULLY unrolled (partial unroll => scratch spill).
struct StageArgs {
  const float* sqrtT;
  float ts_prev, ts_cur;
  int mode_prev;             // -1 none, 0,1,2 stage folds, 3 step-end fold
  float* accum6;             // [PTS][6]
  const float *G3, *B3, *Wg3, *Wb3, *b3;
  float *x_cur, *kx, *kl, *lp_state;
  const float *W0, *b0, *Wg0, *Wb0;
  const u16 *G0, *Bc0;
  const u16* W1b;
  const float *b1, *Wg1, *Wb1;
  const u16 *G1, *Bc1;
  const u16* W2b;
  const float *b2, *Wg2, *Wb2;
  const u16 *G2, *Bc2;
  const float* W3;           // [3][512]
};

__global__ __launch_bounds__(512, 4) void stage_kernel(StageArgs a) {
  __shared__ __align__(16) u16 Hs[64 * HSTR];   // 66.6 KB
  __shared__ float xe[16][3];
  __shared__ float part[8][16][6];
  int tid = threadIdx.x;
  int w = tid >> 6, lane = tid & 63, lr = lane & 15, quad = lane >> 4;
  int n0 = w * 64;
  int p0 = blockIdx.x * 16;
  float s0 = a.sqrtT[0];
  float dt = s0 * s0 * (1.f / 3.f);

  // ---- fold previous stage (thread per point)
  if (tid < 16) {
    int p = p0 + tid;
    float xc0 = a.x_cur[p * 3], xc1 = a.x_cur[p * 3 + 1], xc2 = a.x_cur[p * 3 + 2];
    float o0 = xc0, o1 = xc1, o2 = xc2;
    if (a.mode_prev >= 0) {
      float tp = a.ts_prev * dt;
      float dx[3], gate[3];
      #pragma unroll
      for (int r = 0; r < 3; ++r) {
        float fr = a.accum6[(size_t)p * 6 + r];
        gate[r] = sigf(a.G3[p * 3 + r] + tp * a.Wg3[r * 65]);
        float bias = a.B3[p * 3 + r] + tp * a.Wb3[r * 65];
        dx[r] = fmaf(fr + a.b3[r], gate[r], bias);
      }
      float klv = -(a.accum6[(size_t)p * 6 + 3] * gate[0] +
                    a.accum6[(size_t)p * 6 + 4] * gate[1] +
                    a.accum6[(size_t)p * 6 + 5] * gate[2]);
      int m = a.mode_prev;
      if (m == 0) {
        o0 = xc0 + 0.5f * dt * dx[0]; o1 = xc1 + 0.5f * dt * dx[1]; o2 = xc2 + 0.5f * dt * dx[2];
        a.kx[p * 3] = dx[0]; a.kx[p * 3 + 1] = dx[1]; a.kx[p * 3 + 2] = dx[2];
        a.kl[p] = klv;
      } else if (m == 1) {
        o0 = xc0 + 0.5f * dt * dx[0]; o1 = xc1 + 0.5f * dt * dx[1]; o2 = xc2 + 0.5f * dt * dx[2];
        a.kx[p * 3] += 2.f * dx[0]; a.kx[p * 3 + 1] += 2.f * dx[1]; a.kx[p * 3 + 2] += 2.f * dx[2];
        a.kl[p] += 2.f * klv;
      } else if (m == 2) {
        o0 = xc0 + dt * dx[0]; o1 = xc1 + dt * dx[1]; o2 = xc2 + dt * dx[2];
        a.kx[p * 3] += 2.f * dx[0]; a.kx[p * 3 + 1] += 2.f * dx[1]; a.kx[p * 3 + 2] += 2.f * dx[2];
        a.kl[p] += 2.f * klv;
      } else {
        float sc = dt * (1.f / 6.f);
        o0 = xc0 + sc * (a.kx[p * 3] + dx[0]);
        o1 = xc1 + sc * (a.kx[p * 3 + 1] + dx[1]);
        o2 = xc2 + sc * (a.kx[p * 3 + 2] + dx[2]);
        a.x_cur[p * 3] = o0; a.x_cur[p * 3 + 1] = o1; a.x_cur[p * 3 + 2] = o2;
        a.lp_state[p] += sc * (a.kl[p] + klv);
      }
    }
    xe[tid][0] = o0; xe[tid][1] = o1; xe[tid][2] = o2;
  }
  __syncthreads();

  float t = a.ts_cur * dt;

  // ---- layer0: 32 threads per point, 16 cols each -> H1 in LDS
  {
    int pl = tid >> 5, p = p0 + pl;
    float x0 = xe[pl][0], x1 = xe[pl][1], x2 = xe[pl][2];
    int base_o = (tid & 31) * 16;
    #pragma unroll
    for (int cc = 0; cc < 2; ++cc) {
      int ob = base_o + cc * 8;
      u16x8 g8 = *(const u16x8*)(a.G0 + (size_t)p * 512 + ob);
      u16x8 c8 = *(const u16x8*)(a.Bc0 + (size_t)p * 512 + ob);
      u16x8 oh, od0, od1, od2;
      #pragma unroll
      for (int jj = 0; jj < 8; ++jj) {
        int o = ob + jj;
        float w0 = a.W0[o * 3], w1 = a.W0[o * 3 + 1], w2 = a.W0[o * 3 + 2];
        float u = fmaf(w0, x0, fmaf(w1, x1, w2 * x2)) + a.b0[o];
        float gate = sigf(bf2f(g8[jj]) + t * a.Wg0[o * 65]);
        float bias = bf2f(c8[jj]) + t * a.Wb0[o * 65];
        float z = fmaf(u, gate, bias);
        float h = fast_tanh(z);
        float wm = (1.f - h * h) * gate;
        oh[jj] = f2bf(h);
        od0[jj] = f2bf(wm * w0);
        od1[jj] = f2bf(wm * w1);
        od2[jj] = f2bf(wm * w2);
      }
      size_t hb = (size_t)(pl * 4) * HSTR + ob;
      *(u16x8*)(Hs + hb) = oh;
      *(u16x8*)(Hs + hb + HSTR) = od0;
      *(u16x8*)(Hs + hb + 2 * HSTR) = od1;
      *(u16x8*)(Hs + hb + 3 * HSTR) = od2;
    }
  }
  __syncthreads();

  // ---- layer1 GEMM (64x64 tile per wave)
  f32x4 acc[4][4];
  #pragma unroll
  for (int i = 0; i < 4; ++i)
    #pragma unroll
    for (int j = 0; j < 4; ++j)
      #pragma unroll
      for (int r = 0; r < 4; ++r) acc[i][j][r] = 0.f;
  {
    const u16* wp = a.W1b + ((size_t)(n0 + lr) * 512 + quad * 8);
    #pragma unroll 1
    for (int k0 = 0; k0 < 512; k0 += 32) {
      s16x8 bf[4], af[4];
      #pragma unroll
      for (int j = 0; j < 4; ++j)
        bf[j] = *(const s16x8*)(wp + (size_t)j * 16 * 512 + k0);
      #pragma unroll
      for (int i = 0; i < 4; ++i)
        af[i] = *(const s16x8*)(Hs + (i * 16 + lr) * HSTR + k0 + quad * 8);
      #pragma unroll
      for (int i = 0; i < 4; ++i)
        #pragma unroll
        for (int j = 0; j < 4; ++j)
          acc[i][j] = __builtin_amdgcn_mfma_f32_16x16x32_bf16(af[i], bf[j], acc[i][j], 0, 0, 0);
    }
  }
  __syncthreads();   // all H1 reads done

  // ---- epilogue1 -> H2 in same LDS (FULLY unrolled)
  #pragma unroll
  for (int j = 0; j < 4; ++j) {
    int n = n0 + j * 16 + lr;
    float bvn = a.b1[n];
    float wg0 = a.Wg1[n * 65], wb0 = a.Wb1[n * 65];
    #pragma unroll
    for (int i = 0; i < 4; ++i) {
      int p = p0 + i * 4 + quad;
      float gate = sigf(bf2f(a.G1[(size_t)p * 512 + n]) + t * wg0);
      float bias = bf2f(a.Bc1[(size_t)p * 512 + n]) + t * wb0;
      f32x4 u = acc[i][j];
      float z = fmaf(u[0] + bvn, gate, bias);
      float h = fast_tanh(z);
      float wmf = (1.f - h * h) * gate;
      int row = i * 16 + quad * 4;
      Hs[(size_t)row * HSTR + n] = f2bf(h);
      Hs[(size_t)(row + 1) * HSTR + n] = f2bf(u[1] * wmf);
      Hs[(size_t)(row + 2) * HSTR + n] = f2bf(u[2] * wmf);
      Hs[(size_t)(row + 3) * HSTR + n] = f2bf(u[3] * wmf);
    }
  }
  __syncthreads();

  // ---- layer2 GEMM
  #pragma unroll
  for (int i = 0; i < 4; ++i)
    #pragma unroll
    for (int j = 0; j < 4; ++j)
      #pragma unroll
      for (int r = 0; r < 4; ++r) acc[i][j][r] = 0.f;
  {
    const u16* wp = a.W2b + ((size_t)(n0 + lr) * 512 + quad * 8);
    #pragma unroll 1
    for (int k0 = 0; k0 < 512; k0 += 32) {
      s16x8 bf[4], af[4];
      #pragma unroll
      for (int j = 0; j < 4; ++j)
        bf[j] = *(const s16x8*)(wp + (size_t)j * 16 * 512 + k0);
      #pragma unroll
      for (int i = 0; i < 4; ++i)
        af[i] = *(const s16x8*)(Hs + (i * 16 + lr) * HSTR + k0 + quad * 8);
      #pragma unroll
      for (int i = 0; i < 4; ++i)
        #pragma unroll
        for (int j = 0; j < 4; ++j)
          acc[i][j] = __builtin_amdgcn_mfma_f32_16x16x32_bf16(af[i], bf[j], acc[i][j], 0, 0, 0);
    }
  }

  // ---- epilogue2: gate/tanh + project onto W3 -> 6 partials per point (FULLY unrolled)
  #pragma unroll
  for (int i = 0; i < 4; ++i) {
    float v0 = 0.f, v1 = 0.f, v2 = 0.f, v3 = 0.f, v4 = 0.f, v5 = 0.f;
    int pl = i * 4 + quad;
    int p = p0 + pl;
    #pragma unroll
    for (int j = 0; j < 4; ++j) {
      int n = n0 + j * 16 + lr;
      float bvn = a.b2[n];
      float wg0 = a.Wg2[n * 65], wb0 = a.Wb2[n * 65];
      float gate = sigf(bf2f(a.G2[(size_t)p * 512 + n]) + t * wg0);
      float bias = bf2f(a.Bc2[(size_t)p * 512 + n]) + t * wb0;
      f32x4 u = acc[i][j];
      float z = fmaf(u[0] + bvn, gate, bias);
      float h = fast_tanh(z);
      float wmf = (1.f - h * h) * gate;
      float w30 = a.W3[n], w31 = a.W3[512 + n], w32 = a.W3[1024 + n];
      v0 = fmaf(h, w30, v0);
      v1 = fmaf(h, w31, v1);
      v2 = fmaf(h, w32, v2);
      v3 = fmaf(u[1] * wmf, w30, v3);
      v4 = fmaf(u[2] * wmf, w31, v4);
      v5 = fmaf(u[3] * wmf, w32, v5);
    }
    #pragma unroll
    for (int mask = 1; mask <= 8; mask <<= 1) {
      v0 += __shfl_xor(v0, mask);
      v1 += __shfl_xor(v1, mask);
      v2 += __shfl_xor(v2, mask);
      v3 += __shfl_xor(v3, mask);
      v4 += __shfl_xor(v4, mask);
      v5 += __shfl_xor(v5, mask);
    }
    float val = (lr == 0) ? v0 : (lr == 1) ? v1 : (lr == 2) ? v2
              : (lr == 3) ? v3 : (lr == 4) ? v4 : v5;
    if (lr < 6) part[w][pl][lr] = val;
  }
  __syncthreads();

  if (tid < 96) {
    int pt = tid / 6, d = tid - pt * 6;
    float sum = 0.f;
    #pragma unroll
    for (int ww = 0; ww < 8; ++ww) sum += part[ww][pt][d];
    a.accum6[(size_t)(p0 + pt) * 6 + d] = sum;
  }
}

// ---------------------------------------------------------------- finalize
struct FinArgs {
  const float* sqrtT;
  const float* accum6;
  const float *G3, *B3, *Wg3, *Wb3, *b3;
  float *x_cur, *kx, *kl, *lp_state;
  const float *m2, *v2, *lg2, *be2;
  float* out_x;
};
__global__ void finalize_kernel(FinArgs a) {
  int p = blockIdx.x * 256 + threadIdx.x;
  if (p >= PTS) return;
  float s0 = a.sqrtT[0];
  float dt = s0 * s0 * (1.f / 3.f);
  float tp = 3.f * dt;
  float dx[3], gate[3];
  #pragma unroll
  for (int r = 0; r < 3; ++r) {
    float fr = a.accum6[(size_t)p * 6 + r];
    gate[r] = sigf(a.G3[p * 3 + r] + tp * a.Wg3[r * 65]);
    float bias = a.B3[p * 3 + r] + tp * a.Wb3[r * 65];
    dx[r] = fmaf(fr + a.b3[r], gate[r], bias);
  }
  float klv = -(a.accum6[(size_t)p * 6 + 3] * gate[0] +
                a.accum6[(size_t)p * 6 + 4] * gate[1] +
                a.accum6[(size_t)p * 6 + 5] * gate[2]);
  float sc = dt * (1.f / 6.f);
  #pragma unroll
  for (int r = 0; r < 3; ++r) {
    float xf = a.x_cur[p * 3 + r] + sc * (a.kx[p * 3 + r] + dx[r]);
    a.out_x[p * 3 + r] = (xf - a.m2[r]) * __expf(a.lg2[r]) * rsqrtf(a.v2[r] + BN_EPS) + a.be2[r];
  }
  a.lp_state[p] += sc * (a.kl[p] + klv);
}

__global__ void finish_lp(const float* __restrict__ lp_state,
                          const float* __restrict__ v1, const float* __restrict__ lg1,
                          const float* __restrict__ v2, const float* __restrict__ lg2,
                          float* __restrict__ out) {
  int b = blockIdx.x, tid = threadIdx.x;
  float s = 0.f;
  for (int n = tid; n < 2048; n += 256) s += lp_state[b * 2048 + n];
  __shared__ float red[256];
  red[tid] = s;
  __syncthreads();
  for (int w = 128; w > 0; w >>= 1) {
    if (tid < w) red[tid] += red[tid + w];
    __syncthreads();
  }
  if (tid == 0) {
    float ld = 0.f;
    for (int d = 0; d < 3; ++d) {
      ld += lg1[d] - 0.5f * logf(v1[d] + BN_EPS);
      ld += lg2[d] - 0.5f * logf(v2[d] + BN_EPS);
    }
    out[b] = red[0] - 2048.f * ld;
  }
}

// ---------------------------------------------------------------- launch
extern "C" void kernel_launch(void* const* d_in, const int* in_sizes, int n_in,
                              void* d_out, int out_size, void* d_ws, size_t ws_size,
                              hipStream_t stream) {
  const float* x        = (const float*)d_in[0];
  const float* c        = (const float*)d_in[1];
  const float* bn1_mean = (const float*)d_in[2];
  const float* bn1_var  = (const float*)d_in[3];
  const float* bn1_lg   = (const float*)d_in[4];
  const float* bn1_beta = (const float*)d_in[5];
  const float* bn2_mean = (const float*)d_in[6];
  const float* bn2_var  = (const float*)d_in[7];
  const float* bn2_lg   = (const float*)d_in[8];
  const float* bn2_beta = (const float*)d_in[9];
  const float* sqrtT    = (const float*)d_in[10];
  const float* W0  = (const float*)d_in[11];
  const float* b0  = (const float*)d_in[12];
  const float* Wg0 = (const float*)d_in[13];
  const float* bg0 = (const float*)d_in[14];
  const float* Wb0 = (const float*)d_in[15];
  const float* W1  = (const float*)d_in[16];
  const float* b1  = (const float*)d_in[17];
  const float* Wg1 = (const float*)d_in[18];
  const float* bg1 = (const float*)d_in[19];
  const float* Wb1 = (const float*)d_in[20];
  const float* W2  = (const float*)d_in[21];
  const float* b2  = (const float*)d_in[22];
  const float* Wg2 = (const float*)d_in[23];
  const float* bg2 = (const float*)d_in[24];
  const float* Wb2 = (const float*)d_in[25];
  const float* W3  = (const float*)d_in[26];
  const float* b3  = (const float*)d_in[27];
  const float* Wg3 = (const float*)d_in[28];
  const float* bg3 = (const float*)d_in[29];
  const float* Wb3 = (const float*)d_in[30];

  char* base = (char*)d_ws;
  size_t off = 0;
  auto alloc = [&](size_t bytes) -> void* {
    void* pp = base + off;
    off += (bytes + 255) & ~(size_t)255;
    return pp;
  };
  u16* W1b = (u16*)alloc((size_t)512 * 512 * 2);
  u16* W2b = (u16*)alloc((size_t)512 * 512 * 2);
  u16* cb  = (u16*)alloc((size_t)PTS * 64 * 2);
  u16* Wpack = (u16*)alloc((size_t)6 * 512 * 64 * 2);
  float* bias_pack = (float*)alloc((size_t)3072 * 4);
  u16* GB = (u16*)alloc((size_t)6 * PTS * 512 * 2);
  const size_t SZ = (size_t)PTS * 512;
  u16* G[3]  = {GB, GB + SZ, GB + 2 * SZ};
  u16* Bc[3] = {GB + 3 * SZ, GB + 4 * SZ, GB + 5 * SZ};
  float* G3f = (float*)alloc((size_t)PTS * 3 * 4);
  float* B3f = (float*)alloc((size_t)PTS * 3 * 4);
  float* accum6   = (float*)alloc((size_t)PTS * 6 * 4);
  float* x_cur    = (float*)alloc((size_t)PTS * 3 * 4);
  float* kx       = (float*)alloc((size_t)PTS * 3 * 4);
  float* kl       = (float*)alloc((size_t)PTS * 4);
  float* lp_state = (float*)alloc((size_t)PTS * 4);
  (void)ws_size; (void)in_sizes; (void)n_in; (void)out_size;

  PrepArgs pa{W1, W2, W1b, W2b, c, cb, Wg0, Wg1, Wg2, Wb0, Wb1, Wb2,
              bg0, bg1, bg2, Wpack, bias_pack, x, bn1_mean, bn1_var,
              bn1_lg, bn1_beta, x_cur, lp_state, Wg3, bg3, Wb3, G3f, B3f};
  prep_kernel<<<2048, 256, 0, stream>>>(pa);

  GatesGemmArgs gg{cb, Wpack, bias_pack, GB};
  gates_gemm<<<dim3(64, 24), 256, 0, stream>>>(gg);

  auto ts_of = [](int s) -> float {
    static const float frac[4] = {0.f, 0.5f, 0.5f, 1.f};
    return (float)(s >> 2) + frac[s & 3];
  };

  for (int s = 0; s < 12; ++s) {
    StageArgs sa{sqrtT, (s == 0) ? 0.f : ts_of(s - 1), ts_of(s),
                 (s == 0) ? -1 : ((s - 1) & 3), accum6,
                 G3f, B3f, Wg3, Wb3, b3, x_cur, kx, kl, lp_state,
                 W0, b0, Wg0, Wb0, G[0], Bc[0],
                 W1b, b1, Wg1, Wb1, G[1], Bc[1],
                 W2b, b2, Wg2, Wb2, G[2], Bc[2], W3};
    stage_kernel<<<PTS / 16, 512, 0, stream>>>(sa);
  }

  FinArgs fa{sqrtT, accum6, G3f, B3f, Wg3, Wb3, b3, x_cur, kx, kl,
             lp_state, bn2_mean, bn2_var, bn2_lg, bn2_beta, (float*)d_out};
  finalize_kernel<<<32, 256, 0, stream>>>(fa);
  finish_lp<<<4, 256, 0, stream>>>(lp_state, bn1_var, bn1_lg, bn2_var, bn2_lg,
                                   (float*)d_out + PTS * 3);
}

// Round 9
// 1168.057 us; speedup vs baseline: 1.5565x; 1.0738x over previous
//
#include <hip/hip_runtime.h>

#define PTS 8192          // B*N = 4*2048 points
#define HDIM 512
#define BN_EPS 1e-4f
#define HSTR 520          // LDS row stride (elems)

typedef unsigned short u16;
typedef u16 u16x8 __attribute__((ext_vector_type(8)));
typedef u16 u16x4 __attribute__((ext_vector_type(4)));
typedef short s16x8 __attribute__((ext_vector_type(8)));
typedef float f32x4 __attribute__((ext_vector_type(4)));
typedef float f32x2 __attribute__((ext_vector_type(2)));

__device__ __forceinline__ float bf2f(u16 u) {
  unsigned x = ((unsigned)u) << 16;
  return __builtin_bit_cast(float, x);
}
__device__ __forceinline__ u16 f2bf(float f) {
  unsigned x = __builtin_bit_cast(unsigned, f);
  x += 0x7fffu + ((x >> 16) & 1u);
  return (u16)(x >> 16);
}
__device__ __forceinline__ float sigf(float x) {
  return __builtin_amdgcn_rcpf(1.f + __expf(-x));
}
__device__ __forceinline__ float fast_tanh(float x) {
  float e = __expf(2.f * x);
  return 1.f - 2.f * __builtin_amdgcn_rcpf(e + 1.f);
}
__device__ __forceinline__ void gl2lds16(const u16* g, u16* l) {
  __builtin_amdgcn_global_load_lds(
      (const __attribute__((address_space(1))) void*)g,
      (__attribute__((address_space(3))) void*)l, 16, 0, 0);
}

// ---------------------------------------------------------------- prep
struct PrepArgs {
  const float *W1, *W2;
  u16 *W1b, *W2b;
  const float* c;
  u16* cb;
  const float *Wg0, *Wg1, *Wg2, *Wb0, *Wb1, *Wb2;
  const float *bg0, *bg1, *bg2;
  u16* Wpack;          // [6*512][64] bf16
  float* bias_pack;    // [3072]
  const float *x, *m1, *v1, *lg1, *be1;
  float *x_cur, *lp_state;
  const float *Wg3, *bg3, *Wb3;
  float *G3, *B3;
  const float *W0, *b0, *b1, *b2, *W3;
  float *E0, *E1, *E2;   // packed epilogue params: [512][8], [512][4], [512][8]
};
__global__ void prep_kernel(PrepArgs a) {
  int i = blockIdx.x * 256 + threadIdx.x;   // 0 .. 524287
  if (i < 512 * 512) { a.W1b[i] = f2bf(a.W1[i]); a.W2b[i] = f2bf(a.W2[i]); }
  if (i < PTS * 64) a.cb[i] = f2bf(a.c[i]);
  if (i < 6 * 512 * 64) {
    int sec = i >> 15;
    int within = i & 32767;
    int o = within >> 6, k = within & 63;
    const float* src[6] = {a.Wg0, a.Wg1, a.Wg2, a.Wb0, a.Wb1, a.Wb2};
    a.Wpack[i] = f2bf(src[sec][o * 65 + 1 + k]);
  }
  if (i < 3072) {
    int sec = i >> 9, o = i & 511;
    const float* bgl[3] = {a.bg0, a.bg1, a.bg2};
    a.bias_pack[i] = (sec < 3) ? bgl[sec][o] : 0.f;
  }
  if (i < 512) {
    int o = i;
    a.E0[o * 8 + 0] = a.W0[o * 3];
    a.E0[o * 8 + 1] = a.W0[o * 3 + 1];
    a.E0[o * 8 + 2] = a.W0[o * 3 + 2];
    a.E0[o * 8 + 3] = a.b0[o];
    a.E0[o * 8 + 4] = a.Wg0[o * 65];
    a.E0[o * 8 + 5] = a.Wb0[o * 65];
    a.E0[o * 8 + 6] = 0.f; a.E0[o * 8 + 7] = 0.f;
    a.E1[o * 4 + 0] = a.b1[o];
    a.E1[o * 4 + 1] = a.Wg1[o * 65];
    a.E1[o * 4 + 2] = a.Wb1[o * 65];
    a.E1[o * 4 + 3] = 0.f;
    a.E2[o * 8 + 0] = a.b2[o];
    a.E2[o * 8 + 1] = a.Wg2[o * 65];
    a.E2[o * 8 + 2] = a.Wb2[o * 65];
    a.E2[o * 8 + 3] = a.W3[o];
    a.E2[o * 8 + 4] = a.W3[512 + o];
    a.E2[o * 8 + 5] = a.W3[1024 + o];
    a.E2[o * 8 + 6] = 0.f; a.E2[o * 8 + 7] = 0.f;
  }
  if (i < PTS * 3) {
    int d = i % 3;
    a.x_cur[i] = (a.x[i] - a.m1[d]) * __expf(a.lg1[d]) * rsqrtf(a.v1[d] + BN_EPS) + a.be1[d];
  }
  if (i < PTS) a.lp_state[i] = 0.f;
  {
    int lane = threadIdx.x & 63;
    int p = (blockIdx.x * 256 + threadIdx.x) >> 6;   // 0..8191
    float cv = a.c[(size_t)p * 64 + lane];
    float ag[3], ab[3];
    #pragma unroll
    for (int o = 0; o < 3; ++o) {
      ag[o] = cv * a.Wg3[o * 65 + 1 + lane];
      ab[o] = cv * a.Wb3[o * 65 + 1 + lane];
    }
    #pragma unroll
    for (int off = 32; off > 0; off >>= 1) {
      #pragma unroll
      for (int o = 0; o < 3; ++o) {
        ag[o] += __shfl_xor(ag[o], off);
        ab[o] += __shfl_xor(ab[o], off);
      }
    }
    if (lane == 0) {
      #pragma unroll
      for (int o = 0; o < 3; ++o) {
        a.G3[p * 3 + o] = ag[o] + a.bg3[o];
        a.B3[p * 3 + o] = ab[o];
      }
    }
  }
}

// ---------------------------------------------------------------- gates GEMM
// Output INTERLEAVED: GBi[layer][p][2*col] = G(+bg), [2*col+1] = Bc.
struct GatesGemmArgs {
  const u16 *A, *W;
  const float* bias;
  u16* GBi;                // [3][8192][1024]
};
__global__ __launch_bounds__(256) void gates_gemm(GatesGemmArgs a) {
  __shared__ u16 As[128 * 32];
  __shared__ u16 Bs[128 * 32];
  int tid = threadIdx.x;
  int m0 = blockIdx.x * 128, n0 = blockIdx.y * 128;
  int wave = tid >> 6, lane = tid & 63;
  int wm = (wave & 1) * 64, wn = (wave >> 1) * 64;
  int lr = lane & 15, quad = lane >> 4;

  int rowS = tid >> 2, colS = (tid & 3) * 8;
  const u16* gA0 = a.A + (size_t)(m0 + rowS) * 64 + colS;
  const u16* gB0 = a.W + (size_t)(n0 + rowS) * 64 + colS;
  u16* sA0 = &As[tid * 8];
  u16* sA1 = &As[2048 + tid * 8];
  u16* sB0 = &Bs[tid * 8];
  u16* sB1 = &Bs[2048 + tid * 8];

  f32x4 acc[4][4];
  #pragma unroll
  for (int i = 0; i < 4; ++i)
    #pragma unroll
    for (int j = 0; j < 4; ++j)
      #pragma unroll
      for (int r = 0; r < 4; ++r) acc[i][j][r] = 0.f;

  for (int k0 = 0; k0 < 64; k0 += 32) {
    if (k0) __syncthreads();
    gl2lds16(gA0 + k0, sA0);
    gl2lds16(gA0 + (size_t)64 * 64 + k0, sA1);
    gl2lds16(gB0 + k0, sB0);
    gl2lds16(gB0 + (size_t)64 * 64 + k0, sB1);
    __syncthreads();
    s16x8 af[4], bfr[4];
    #pragma unroll
    for (int i = 0; i < 4; ++i)
      af[i] = *(const s16x8*)&As[(wm + i * 16 + lr) * 32 + quad * 8];
    #pragma unroll
    for (int j = 0; j < 4; ++j)
      bfr[j] = *(const s16x8*)&Bs[(wn + j * 16 + lr) * 32 + quad * 8];
    #pragma unroll
    for (int i = 0; i < 4; ++i)
      #pragma unroll
      for (int j = 0; j < 4; ++j)
        acc[i][j] = __builtin_amdgcn_mfma_f32_16x16x32_bf16(af[i], bfr[j], acc[i][j], 0, 0, 0);
  }

  #pragma unroll
  for (int j = 0; j < 4; ++j) {
    int n = n0 + wn + j * 16 + lr;
    int sec = n >> 9, col = n & 511;
    int l = (sec < 3) ? sec : sec - 3;
    int off = col * 2 + ((sec < 3) ? 0 : 1);
    float bv = a.bias[n];
    u16* outp = a.GBi + (size_t)l * PTS * 1024 + off;
    #pragma unroll
    for (int i = 0; i < 4; ++i) {
      int mrow = m0 + wm + i * 16 + quad * 4;
      #pragma unroll
      for (int r = 0; r < 4; ++r)
        outp[(size_t)(mrow + r) * 1024] = f2bf(acc[i][j][r] + bv);
    }
  }
}

// ---------------------------------------------------------------- per-stage kernel
// 512 blocks x 512 threads (8 waves); block owns 16 points (64 m-rows).
// Gate dwords for each epilogue are PREFETCHED before the preceding K-loop.
struct StageArgs {
  const float* sqrtT;
  float ts_prev, ts_cur;
  int mode_prev;             // -1 none, 0,1,2 stage folds, 3 step-end fold
  float* accum6;             // [PTS][6]
  const float *G3, *B3, *Wg3, *Wb3, *b3;
  float *x_cur, *kx, *kl, *lp_state;
  const u16 *GBi0, *GBi1, *GBi2;   // interleaved gate tables [PTS][1024]
  const float *E0, *E1, *E2;       // packed params
  const u16 *W1b, *W2b;
};

__global__ __launch_bounds__(512, 4) void stage_kernel(StageArgs a) {
  __shared__ __align__(16) u16 Hs[64 * HSTR];   // 66.6 KB
  __shared__ float xe[16][3];
  __shared__ float part[8][16][6];
  int tid = threadIdx.x;
  int w = tid >> 6, lane = tid & 63, lr = lane & 15, quad = lane >> 4;
  int n0 = w * 64;
  int p0 = blockIdx.x * 16;
  float s0 = a.sqrtT[0];
  float dt = s0 * s0 * (1.f / 3.f);

  // ---- issue L0 gate loads EARLY (independent of fold)
  int pl0 = tid >> 5;
  int base_o = (tid & 31) * 16;
  const u16* g0row = a.GBi0 + (size_t)(p0 + pl0) * 1024 + 2 * base_o;
  u16x8 gc0 = *(const u16x8*)(g0row);
  u16x8 gc1 = *(const u16x8*)(g0row + 8);
  u16x8 gc2 = *(const u16x8*)(g0row + 16);
  u16x8 gc3 = *(const u16x8*)(g0row + 24);

  // ---- fold previous stage (thread per point)
  if (tid < 16) {
    int p = p0 + tid;
    float xc0 = a.x_cur[p * 3], xc1 = a.x_cur[p * 3 + 1], xc2 = a.x_cur[p * 3 + 2];
    float o0 = xc0, o1 = xc1, o2 = xc2;
    if (a.mode_prev >= 0) {
      float tp = a.ts_prev * dt;
      float dx[3], gate[3];
      #pragma unroll
      for (int r = 0; r < 3; ++r) {
        float fr = a.accum6[(size_t)p * 6 + r];
        gate[r] = sigf(a.G3[p * 3 + r] + tp * a.Wg3[r * 65]);
        float bias = a.B3[p * 3 + r] + tp * a.Wb3[r * 65];
        dx[r] = fmaf(fr + a.b3[r], gate[r], bias);
      }
      float klv = -(a.accum6[(size_t)p * 6 + 3] * gate[0] +
                    a.accum6[(size_t)p * 6 + 4] * gate[1] +
                    a.accum6[(size_t)p * 6 + 5] * gate[2]);
      int m = a.mode_prev;
      if (m == 0) {
        o0 = xc0 + 0.5f * dt * dx[0]; o1 = xc1 + 0.5f * dt * dx[1]; o2 = xc2 + 0.5f * dt * dx[2];
        a.kx[p * 3] = dx[0]; a.kx[p * 3 + 1] = dx[1]; a.kx[p * 3 + 2] = dx[2];
        a.kl[p] = klv;
      } else if (m == 1) {
        o0 = xc0 + 0.5f * dt * dx[0]; o1 = xc1 + 0.5f * dt * dx[1]; o2 = xc2 + 0.5f * dt * dx[2];
        a.kx[p * 3] += 2.f * dx[0]; a.kx[p * 3 + 1] += 2.f * dx[1]; a.kx[p * 3 + 2] += 2.f * dx[2];
        a.kl[p] += 2.f * klv;
      } else if (m == 2) {
        o0 = xc0 + dt * dx[0]; o1 = xc1 + dt * dx[1]; o2 = xc2 + dt * dx[2];
        a.kx[p * 3] += 2.f * dx[0]; a.kx[p * 3 + 1] += 2.f * dx[1]; a.kx[p * 3 + 2] += 2.f * dx[2];
        a.kl[p] += 2.f * klv;
      } else {
        float sc = dt * (1.f / 6.f);
        o0 = xc0 + sc * (a.kx[p * 3] + dx[0]);
        o1 = xc1 + sc * (a.kx[p * 3 + 1] + dx[1]);
        o2 = xc2 + sc * (a.kx[p * 3 + 2] + dx[2]);
        a.x_cur[p * 3] = o0; a.x_cur[p * 3 + 1] = o1; a.x_cur[p * 3 + 2] = o2;
        a.lp_state[p] += sc * (a.kl[p] + klv);
      }
    }
    xe[tid][0] = o0; xe[tid][1] = o1; xe[tid][2] = o2;
  }
  __syncthreads();

  float t = a.ts_cur * dt;

  // ---- layer0: 32 threads per point, 16 cols each -> H1 in LDS
  {
    float x0 = xe[pl0][0], x1 = xe[pl0][1], x2 = xe[pl0][2];
    u16x8 gcv[4] = {gc0, gc1, gc2, gc3};
    #pragma unroll
    for (int cc = 0; cc < 4; ++cc) {
      u16x8 v = gcv[cc];
      u16x4 oh, od0, od1, od2;
      #pragma unroll
      for (int k = 0; k < 4; ++k) {
        int o = base_o + cc * 4 + k;
        f32x4 e = *(const f32x4*)(a.E0 + (size_t)o * 8);
        f32x2 e2 = *(const f32x2*)(a.E0 + (size_t)o * 8 + 4);
        float u = fmaf(e[0], x0, fmaf(e[1], x1, e[2] * x2)) + e[3];
        float gate = sigf(bf2f(v[2 * k]) + t * e2[0]);
        float bias = bf2f(v[2 * k + 1]) + t * e2[1];
        float z = fmaf(u, gate, bias);
        float h = fast_tanh(z);
        float wm = (1.f - h * h) * gate;
        oh[k] = f2bf(h);
        od0[k] = f2bf(wm * e[0]);
        od1[k] = f2bf(wm * e[1]);
        od2[k] = f2bf(wm * e[2]);
      }
      size_t hb = (size_t)(pl0 * 4) * HSTR + base_o + cc * 4;
      *(u16x4*)(Hs + hb) = oh;
      *(u16x4*)(Hs + hb + HSTR) = od0;
      *(u16x4*)(Hs + hb + 2 * HSTR) = od1;
      *(u16x4*)(Hs + hb + 3 * HSTR) = od2;
    }
  }

  // ---- prefetch epilogue-1 gate dwords (hidden behind GEMM1)
  unsigned g1v[4][4];
  #pragma unroll
  for (int j = 0; j < 4; ++j)
    #pragma unroll
    for (int i = 0; i < 4; ++i) {
      int n = n0 + j * 16 + lr;
      int p = p0 + i * 4 + quad;
      g1v[j][i] = *(const unsigned*)(a.GBi1 + (size_t)p * 1024 + 2 * n);
    }
  __syncthreads();

  // ---- layer1 GEMM (64x64 tile per wave)
  f32x4 acc[4][4];
  #pragma unroll
  for (int i = 0; i < 4; ++i)
    #pragma unroll
    for (int j = 0; j < 4; ++j)
      #pragma unroll
      for (int r = 0; r < 4; ++r) acc[i][j][r] = 0.f;
  {
    const u16* wp = a.W1b + ((size_t)(n0 + lr) * 512 + quad * 8);
    #pragma unroll 2
    for (int k0 = 0; k0 < 512; k0 += 32) {
      s16x8 bf[4], af[4];
      #pragma unroll
      for (int j = 0; j < 4; ++j)
        bf[j] = *(const s16x8*)(wp + (size_t)j * 16 * 512 + k0);
      #pragma unroll
      for (int i = 0; i < 4; ++i)
        af[i] = *(const s16x8*)(Hs + (i * 16 + lr) * HSTR + k0 + quad * 8);
      #pragma unroll
      for (int i = 0; i < 4; ++i)
        #pragma unroll
        for (int j = 0; j < 4; ++j)
          acc[i][j] = __builtin_amdgcn_mfma_f32_16x16x32_bf16(af[i], bf[j], acc[i][j], 0, 0, 0);
    }
  }
  __syncthreads();   // all H1 reads done

  // ---- epilogue1 -> H2 in same LDS (FULLY unrolled)
  #pragma unroll
  for (int j = 0; j < 4; ++j) {
    int n = n0 + j * 16 + lr;
    f32x4 e1 = *(const f32x4*)(a.E1 + (size_t)n * 4);
    #pragma unroll
    for (int i = 0; i < 4; ++i) {
      unsigned d = g1v[j][i];
      float gate = sigf(bf2f((u16)(d & 0xffffu)) + t * e1[1]);
      float bias = bf2f((u16)(d >> 16)) + t * e1[2];
      f32x4 u = acc[i][j];
      float z = fmaf(u[0] + e1[0], gate, bias);
      float h = fast_tanh(z);
      float wmf = (1.f - h * h) * gate;
      int row = i * 16 + quad * 4;
      Hs[(size_t)row * HSTR + n] = f2bf(h);
      Hs[(size_t)(row + 1) * HSTR + n] = f2bf(u[1] * wmf);
      Hs[(size_t)(row + 2) * HSTR + n] = f2bf(u[2] * wmf);
      Hs[(size_t)(row + 3) * HSTR + n] = f2bf(u[3] * wmf);
    }
  }

  // ---- prefetch epilogue-2 gate dwords (hidden behind GEMM2)
  unsigned g2v[4][4];
  #pragma unroll
  for (int j = 0; j < 4; ++j)
    #pragma unroll
    for (int i = 0; i < 4; ++i) {
      int n = n0 + j * 16 + lr;
      int p = p0 + i * 4 + quad;
      g2v[j][i] = *(const unsigned*)(a.GBi2 + (size_t)p * 1024 + 2 * n);
    }
  __syncthreads();

  // ---- layer2 GEMM
  #pragma unroll
  for (int i = 0; i < 4; ++i)
    #pragma unroll
    for (int j = 0; j < 4; ++j)
      #pragma unroll
      for (int r = 0; r < 4; ++r) acc[i][j][r] = 0.f;
  {
    const u16* wp = a.W2b + ((size_t)(n0 + lr) * 512 + quad * 8);
    #pragma unroll 2
    for (int k0 = 0; k0 < 512; k0 += 32) {
      s16x8 bf[4], af[4];
      #pragma unroll
      for (int j = 0; j < 4; ++j)
        bf[j] = *(const s16x8*)(wp + (size_t)j * 16 * 512 + k0);
      #pragma unroll
      for (int i = 0; i < 4; ++i)
        af[i] = *(const s16x8*)(Hs + (i * 16 + lr) * HSTR + k0 + quad * 8);
      #pragma unroll
      for (int i = 0; i < 4; ++i)
        #pragma unroll
        for (int j = 0; j < 4; ++j)
          acc[i][j] = __builtin_amdgcn_mfma_f32_16x16x32_bf16(af[i], bf[j], acc[i][j], 0, 0, 0);
    }
  }

  // ---- epilogue2: gate/tanh + project onto W3 -> 6 partials per point
  #pragma unroll
  for (int i = 0; i < 4; ++i) {
    float v0 = 0.f, v1 = 0.f, v2 = 0.f, v3 = 0.f, v4 = 0.f, v5 = 0.f;
    int pl = i * 4 + quad;
    #pragma unroll
    for (int j = 0; j < 4; ++j) {
      int n = n0 + j * 16 + lr;
      f32x4 ea = *(const f32x4*)(a.E2 + (size_t)n * 8);
      f32x2 eb = *(const f32x2*)(a.E2 + (size_t)n * 8 + 4);
      unsigned d = g2v[j][i];
      float gate = sigf(bf2f((u16)(d & 0xffffu)) + t * ea[1]);
      float bias = bf2f((u16)(d >> 16)) + t * ea[2];
      f32x4 u = acc[i][j];
      float z = fmaf(u[0] + ea[0], gate, bias);
      float h = fast_tanh(z);
      float wmf = (1.f - h * h) * gate;
      float w30 = ea[3], w31 = eb[0], w32 = eb[1];
      v0 = fmaf(h, w30, v0);
      v1 = fmaf(h, w31, v1);
      v2 = fmaf(h, w32, v2);
      v3 = fmaf(u[1] * wmf, w30, v3);
      v4 = fmaf(u[2] * wmf, w31, v4);
      v5 = fmaf(u[3] * wmf, w32, v5);
    }
    #pragma unroll
    for (int mask = 1; mask <= 8; mask <<= 1) {
      v0 += __shfl_xor(v0, mask);
      v1 += __shfl_xor(v1, mask);
      v2 += __shfl_xor(v2, mask);
      v3 += __shfl_xor(v3, mask);
      v4 += __shfl_xor(v4, mask);
      v5 += __shfl_xor(v5, mask);
    }
    float val = (lr == 0) ? v0 : (lr == 1) ? v1 : (lr == 2) ? v2
              : (lr == 3) ? v3 : (lr == 4) ? v4 : v5;
    if (lr < 6) part[w][pl][lr] = val;
  }
  __syncthreads();

  if (tid < 96) {
    int pt = tid / 6, d = tid - pt * 6;
    float sum = 0.f;
    #pragma unroll
    for (int ww = 0; ww < 8; ++ww) sum += part[ww][pt][d];
    a.accum6[(size_t)(p0 + pt) * 6 + d] = sum;
  }
}

// ---------------------------------------------------------------- finalize
struct FinArgs {
  const float* sqrtT;
  const float* accum6;
  const float *G3, *B3, *Wg3, *Wb3, *b3;
  float *x_cur, *kx, *kl, *lp_state;
  const float *m2, *v2, *lg2, *be2;
  float* out_x;
};
__global__ void finalize_kernel(FinArgs a) {
  int p = blockIdx.x * 256 + threadIdx.x;
  if (p >= PTS) return;
  float s0 = a.sqrtT[0];
  float dt = s0 * s0 * (1.f / 3.f);
  float tp = 3.f * dt;
  float dx[3], gate[3];
  #pragma unroll
  for (int r = 0; r < 3; ++r) {
    float fr = a.accum6[(size_t)p * 6 + r];
    gate[r] = sigf(a.G3[p * 3 + r] + tp * a.Wg3[r * 65]);
    float bias = a.B3[p * 3 + r] + tp * a.Wb3[r * 65];
    dx[r] = fmaf(fr + a.b3[r], gate[r], bias);
  }
  float klv = -(a.accum6[(size_t)p * 6 + 3] * gate[0] +
                a.accum6[(size_t)p * 6 + 4] * gate[1] +
                a.accum6[(size_t)p * 6 + 5] * gate[2]);
  float sc = dt * (1.f / 6.f);
  #pragma unroll
  for (int r = 0; r < 3; ++r) {
    float xf = a.x_cur[p * 3 + r] + sc * (a.kx[p * 3 + r] + dx[r]);
    a.out_x[p * 3 + r] = (xf - a.m2[r]) * __expf(a.lg2[r]) * rsqrtf(a.v2[r] + BN_EPS) + a.be2[r];
  }
  a.lp_state[p] += sc * (a.kl[p] + klv);
}

__global__ void finish_lp(const float* __restrict__ lp_state,
                          const float* __restrict__ v1, const float* __restrict__ lg1,
                          const float* __restrict__ v2, const float* __restrict__ lg2,
                          float* __restrict__ out) {
  int b = blockIdx.x, tid = threadIdx.x;
  float s = 0.f;
  for (int n = tid; n < 2048; n += 256) s += lp_state[b * 2048 + n];
  __shared__ float red[256];
  red[tid] = s;
  __syncthreads();
  for (int w = 128; w > 0; w >>= 1) {
    if (tid < w) red[tid] += red[tid + w];
    __syncthreads();
  }
  if (tid == 0) {
    float ld = 0.f;
    for (int d = 0; d < 3; ++d) {
      ld += lg1[d] - 0.5f * logf(v1[d] + BN_EPS);
      ld += lg2[d] - 0.5f * logf(v2[d] + BN_EPS);
    }
    out[b] = red[0] - 2048.f * ld;
  }
}

// ---------------------------------------------------------------- launch
extern "C" void kernel_launch(void* const* d_in, const int* in_sizes, int n_in,
                              void* d_out, int out_size, void* d_ws, size_t ws_size,
                              hipStream_t stream) {
  const float* x        = (const float*)d_in[0];
  const float* c        = (const float*)d_in[1];
  const float* bn1_mean = (const float*)d_in[2];
  const float* bn1_var  = (const float*)d_in[3];
  const float* bn1_lg   = (const float*)d_in[4];
  const float* bn1_beta = (const float*)d_in[5];
  const float* bn2_mean = (const float*)d_in[6];
  const float* bn2_var  = (const float*)d_in[7];
  const float* bn2_lg   = (const float*)d_in[8];
  const float* bn2_beta = (const float*)d_in[9];
  const float* sqrtT    = (const float*)d_in[10];
  const float* W0  = (const float*)d_in[11];
  const float* b0  = (const float*)d_in[12];
  const float* Wg0 = (const float*)d_in[13];
  const float* bg0 = (const float*)d_in[14];
  const float* Wb0 = (const float*)d_in[15];
  const float* W1  = (const float*)d_in[16];
  const float* b1  = (const float*)d_in[17];
  const float* Wg1 = (const float*)d_in[18];
  const float* bg1 = (const float*)d_in[19];
  const float* Wb1 = (const float*)d_in[20];
  const float* W2  = (const float*)d_in[21];
  const float* b2  = (const float*)d_in[22];
  const float* Wg2 = (const float*)d_in[23];
  const float* bg2 = (const float*)d_in[24];
  const float* Wb2 = (const float*)d_in[25];
  const float* W3  = (const float*)d_in[26];
  const float* b3  = (const float*)d_in[27];
  const float* Wg3 = (const float*)d_in[28];
  const float* bg3 = (const float*)d_in[29];
  const float* Wb3 = (const float*)d_in[30];

  char* base = (char*)d_ws;
  size_t off = 0;
  auto alloc = [&](size_t bytes) -> void* {
    void* pp = base + off;
    off += (bytes + 255) & ~(size_t)255;
    return pp;
  };
  u16* W1b = (u16*)alloc((size_t)512 * 512 * 2);
  u16* W2b = (u16*)alloc((size_t)512 * 512 * 2);
  u16* cb  = (u16*)alloc((size_t)PTS * 64 * 2);
  u16* Wpack = (u16*)alloc((size_t)6 * 512 * 64 * 2);
  float* bias_pack = (float*)alloc((size_t)3072 * 4);
  u16* GBi = (u16*)alloc((size_t)3 * PTS * 1024 * 2);
  const size_t SZi = (size_t)PTS * 1024;
  u16* GBi0 = GBi;
  u16* GBi1 = GBi + SZi;
  u16* GBi2 = GBi + 2 * SZi;
  float* G3f = (float*)alloc((size_t)PTS * 3 * 4);
  float* B3f = (float*)alloc((size_t)PTS * 3 * 4);
  float* E0 = (float*)alloc((size_t)512 * 8 * 4);
  float* E1 = (float*)alloc((size_t)512 * 4 * 4);
  float* E2 = (float*)alloc((size_t)512 * 8 * 4);
  float* accum6   = (float*)alloc((size_t)PTS * 6 * 4);
  float* x_cur    = (float*)alloc((size_t)PTS * 3 * 4);
  float* kx       = (float*)alloc((size_t)PTS * 3 * 4);
  float* kl       = (float*)alloc((size_t)PTS * 4);
  float* lp_state = (float*)alloc((size_t)PTS * 4);
  (void)ws_size; (void)in_sizes; (void)n_in; (void)out_size;

  PrepArgs pa{W1, W2, W1b, W2b, c, cb, Wg0, Wg1, Wg2, Wb0, Wb1, Wb2,
              bg0, bg1, bg2, Wpack, bias_pack, x, bn1_mean, bn1_var,
              bn1_lg, bn1_beta, x_cur, lp_state, Wg3, bg3, Wb3, G3f, B3f,
              W0, b0, b1, b2, W3, E0, E1, E2};
  prep_kernel<<<2048, 256, 0, stream>>>(pa);

  GatesGemmArgs gg{cb, Wpack, bias_pack, GBi};
  gates_gemm<<<dim3(64, 24), 256, 0, stream>>>(gg);

  auto ts_of = [](int s) -> float {
    static const float frac[4] = {0.f, 0.5f, 0.5f, 1.f};
    return (float)(s >> 2) + frac[s & 3];
  };

  for (int s = 0; s < 12; ++s) {
    StageArgs sa{sqrtT, (s == 0) ? 0.f : ts_of(s - 1), ts_of(s),
                 (s == 0) ? -1 : ((s - 1) & 3), accum6,
                 G3f, B3f, Wg3, Wb3, b3, x_cur, kx, kl, lp_state,
                 GBi0, GBi1, GBi2, E0, E1, E2, W1b, W2b};
    stage_kernel<<<PTS / 16, 512, 0, stream>>>(sa);
  }

  FinArgs fa{sqrtT, accum6, G3f, B3f, Wg3, Wb3, b3, x_cur, kx, kl,
             lp_state, bn2_mean, bn2_var, bn2_lg, bn2_beta, (float*)d_out};
  finalize_kernel<<<32, 256, 0, stream>>>(fa);
  finish_lp<<<4, 256, 0, stream>>>(lp_state, bn1_var, bn1_lg, bn2_var, bn2_lg,
                                   (float*)d_out + PTS * 3);
}

// Round 10
// 1161.998 us; speedup vs baseline: 1.5646x; 1.0052x over previous
//
#include <hip/hip_runtime.h>
#include <hip/hip_fp8.h>

#define PTS 8192          // B*N = 4*2048 points
#define HDIM 512
#define BN_EPS 1e-4f
#define HSTRB 528         // LDS row stride in BYTES (fp8 cols); 528/4=132 dwords == 4 mod 32 banks
#define TS 256.0f         // tangent-stream scale (keeps JVP streams out of e4m3 subnormals)

typedef unsigned short u16;
typedef unsigned char u8;
typedef long long i64;
typedef u16 u16x8 __attribute__((ext_vector_type(8)));
typedef short s16x8 __attribute__((ext_vector_type(8)));
typedef float f32x4 __attribute__((ext_vector_type(4)));
typedef float f32x2 __attribute__((ext_vector_type(2)));

__device__ __forceinline__ float bf2f(u16 u) {
  unsigned x = ((unsigned)u) << 16;
  return __builtin_bit_cast(float, x);
}
__device__ __forceinline__ u16 f2bf(float f) {
  unsigned x = __builtin_bit_cast(unsigned, f);
  x += 0x7fffu + ((x >> 16) & 1u);
  return (u16)(x >> 16);
}
__device__ __forceinline__ u8 f2f8(float x) {
  __hip_fp8_e4m3 v(x);
  return __builtin_bit_cast(u8, v);
}
__device__ __forceinline__ float sigf(float x) {
  return __builtin_amdgcn_rcpf(1.f + __expf(-x));
}
__device__ __forceinline__ float fast_tanh(float x) {
  float e = __expf(2.f * x);
  return 1.f - 2.f * __builtin_amdgcn_rcpf(e + 1.f);
}
__device__ __forceinline__ void gl2lds16(const u16* g, u16* l) {
  __builtin_amdgcn_global_load_lds(
      (const __attribute__((address_space(1))) void*)g,
      (__attribute__((address_space(3))) void*)l, 16, 0, 0);
}

// ---------------------------------------------------------------- prep
struct PrepArgs {
  const float *W1, *W2;
  u8 *W1f8, *W2f8;     // fp8 e4m3 [512][512]
  const float* c;
  u16* cb;
  const float *Wg0, *Wg1, *Wg2, *Wb0, *Wb1, *Wb2;
  const float *bg0, *bg1, *bg2;
  u16* Wpack;          // [6*512][64] bf16
  float* bias_pack;    // [3072]
  const float *x, *m1, *v1, *lg1, *be1;
  float *x_cur, *lp_state;
  const float *Wg3, *bg3, *Wb3;
  float *G3, *B3;
  const float *W0, *b0, *b1, *b2, *W3;
  float *E0, *E1, *E2;   // packed epilogue params
};
__global__ void prep_kernel(PrepArgs a) {
  int i = blockIdx.x * 256 + threadIdx.x;   // 0 .. 524287
  if (i < 512 * 512) { a.W1f8[i] = f2f8(a.W1[i]); a.W2f8[i] = f2f8(a.W2[i]); }
  if (i < PTS * 64) a.cb[i] = f2bf(a.c[i]);
  if (i < 6 * 512 * 64) {
    int sec = i >> 15;
    int within = i & 32767;
    int o = within >> 6, k = within & 63;
    const float* src[6] = {a.Wg0, a.Wg1, a.Wg2, a.Wb0, a.Wb1, a.Wb2};
    a.Wpack[i] = f2bf(src[sec][o * 65 + 1 + k]);
  }
  if (i < 3072) {
    int sec = i >> 9, o = i & 511;
    const float* bgl[3] = {a.bg0, a.bg1, a.bg2};
    a.bias_pack[i] = (sec < 3) ? bgl[sec][o] : 0.f;
  }
  if (i < 512) {
    int o = i;
    a.E0[o * 8 + 0] = a.W0[o * 3];
    a.E0[o * 8 + 1] = a.W0[o * 3 + 1];
    a.E0[o * 8 + 2] = a.W0[o * 3 + 2];
    a.E0[o * 8 + 3] = a.b0[o];
    a.E0[o * 8 + 4] = a.Wg0[o * 65];
    a.E0[o * 8 + 5] = a.Wb0[o * 65];
    a.E0[o * 8 + 6] = 0.f; a.E0[o * 8 + 7] = 0.f;
    a.E1[o * 4 + 0] = a.b1[o];
    a.E1[o * 4 + 1] = a.Wg1[o * 65];
    a.E1[o * 4 + 2] = a.Wb1[o * 65];
    a.E1[o * 4 + 3] = 0.f;
    a.E2[o * 8 + 0] = a.b2[o];
    a.E2[o * 8 + 1] = a.Wg2[o * 65];
    a.E2[o * 8 + 2] = a.Wb2[o * 65];
    a.E2[o * 8 + 3] = a.W3[o];
    a.E2[o * 8 + 4] = a.W3[512 + o];
    a.E2[o * 8 + 5] = a.W3[1024 + o];
    a.E2[o * 8 + 6] = 0.f; a.E2[o * 8 + 7] = 0.f;
  }
  if (i < PTS * 3) {
    int d = i % 3;
    a.x_cur[i] = (a.x[i] - a.m1[d]) * __expf(a.lg1[d]) * rsqrtf(a.v1[d] + BN_EPS) + a.be1[d];
  }
  if (i < PTS) a.lp_state[i] = 0.f;
  {
    int lane = threadIdx.x & 63;
    int p = (blockIdx.x * 256 + threadIdx.x) >> 6;   // 0..8191
    float cv = a.c[(size_t)p * 64 + lane];
    float ag[3], ab[3];
    #pragma unroll
    for (int o = 0; o < 3; ++o) {
      ag[o] = cv * a.Wg3[o * 65 + 1 + lane];
      ab[o] = cv * a.Wb3[o * 65 + 1 + lane];
    }
    #pragma unroll
    for (int off = 32; off > 0; off >>= 1) {
      #pragma unroll
      for (int o = 0; o < 3; ++o) {
        ag[o] += __shfl_xor(ag[o], off);
        ab[o] += __shfl_xor(ab[o], off);
      }
    }
    if (lane == 0) {
      #pragma unroll
      for (int o = 0; o < 3; ++o) {
        a.G3[p * 3 + o] = ag[o] + a.bg3[o];
        a.B3[p * 3 + o] = ab[o];
      }
    }
  }
}

// ---------------------------------------------------------------- gates GEMM (bf16, proven)
// Output INTERLEAVED: GBi[layer][p][2*col] = G(+bg), [2*col+1] = Bc.
struct GatesGemmArgs {
  const u16 *A, *W;
  const float* bias;
  u16* GBi;                // [3][8192][1024]
};
__global__ __launch_bounds__(256) void gates_gemm(GatesGemmArgs a) {
  __shared__ u16 As[128 * 32];
  __shared__ u16 Bs[128 * 32];
  int tid = threadIdx.x;
  int m0 = blockIdx.x * 128, n0 = blockIdx.y * 128;
  int wave = tid >> 6, lane = tid & 63;
  int wm = (wave & 1) * 64, wn = (wave >> 1) * 64;
  int lr = lane & 15, quad = lane >> 4;

  int rowS = tid >> 2, colS = (tid & 3) * 8;
  const u16* gA0 = a.A + (size_t)(m0 + rowS) * 64 + colS;
  const u16* gB0 = a.W + (size_t)(n0 + rowS) * 64 + colS;
  u16* sA0 = &As[tid * 8];
  u16* sA1 = &As[2048 + tid * 8];
  u16* sB0 = &Bs[tid * 8];
  u16* sB1 = &Bs[2048 + tid * 8];

  f32x4 acc[4][4];
  #pragma unroll
  for (int i = 0; i < 4; ++i)
    #pragma unroll
    for (int j = 0; j < 4; ++j)
      #pragma unroll
      for (int r = 0; r < 4; ++r) acc[i][j][r] = 0.f;

  for (int k0 = 0; k0 < 64; k0 += 32) {
    if (k0) __syncthreads();
    gl2lds16(gA0 + k0, sA0);
    gl2lds16(gA0 + (size_t)64 * 64 + k0, sA1);
    gl2lds16(gB0 + k0, sB0);
    gl2lds16(gB0 + (size_t)64 * 64 + k0, sB1);
    __syncthreads();
    s16x8 af[4], bfr[4];
    #pragma unroll
    for (int i = 0; i < 4; ++i)
      af[i] = *(const s16x8*)&As[(wm + i * 16 + lr) * 32 + quad * 8];
    #pragma unroll
    for (int j = 0; j < 4; ++j)
      bfr[j] = *(const s16x8*)&Bs[(wn + j * 16 + lr) * 32 + quad * 8];
    #pragma unroll
    for (int i = 0; i < 4; ++i)
      #pragma unroll
      for (int j = 0; j < 4; ++j)
        acc[i][j] = __builtin_amdgcn_mfma_f32_16x16x32_bf16(af[i], bfr[j], acc[i][j], 0, 0, 0);
  }

  #pragma unroll
  for (int j = 0; j < 4; ++j) {
    int n = n0 + wn + j * 16 + lr;
    int sec = n >> 9, col = n & 511;
    int l = (sec < 3) ? sec : sec - 3;
    int off = col * 2 + ((sec < 3) ? 0 : 1);
    float bv = a.bias[n];
    u16* outp = a.GBi + (size_t)l * PTS * 1024 + off;
    #pragma unroll
    for (int i = 0; i < 4; ++i) {
      int mrow = m0 + wm + i * 16 + quad * 4;
      #pragma unroll
      for (int r = 0; r < 4; ++r)
        outp[(size_t)(mrow + r) * 1024] = f2bf(acc[i][j][r] + bv);
    }
  }
}

// ---------------------------------------------------------------- per-stage kernel (fp8 GEMMs)
struct StageArgs {
  const float* sqrtT;
  float ts_prev, ts_cur;
  int mode_prev;             // -1 none, 0,1,2 stage folds, 3 step-end fold
  float* accum6;             // [PTS][6]
  const float *G3, *B3, *Wg3, *Wb3, *b3;
  float *x_cur, *kx, *kl, *lp_state;
  const u16 *GBi0, *GBi1, *GBi2;   // interleaved gate tables [PTS][1024]
  const float *E0, *E1, *E2;       // packed params
  const u8 *W1f8, *W2f8;           // fp8 weights [512][512]
};

__global__ __launch_bounds__(512, 4) void stage_kernel(StageArgs a) {
  __shared__ __align__(16) u8 Hs[64 * HSTRB];   // 33.8 KB (fp8)
  __shared__ float xe[16][3];
  __shared__ float part[8][16][6];
  int tid = threadIdx.x;
  int w = tid >> 6, lane = tid & 63, lr = lane & 15, quad = lane >> 4;
  int n0 = w * 64;
  int p0 = blockIdx.x * 16;
  float s0 = a.sqrtT[0];
  float dt = s0 * s0 * (1.f / 3.f);

  // ---- issue L0 gate loads EARLY (independent of fold)
  int pl0 = tid >> 5;
  int base_o = (tid & 31) * 16;
  const u16* g0row = a.GBi0 + (size_t)(p0 + pl0) * 1024 + 2 * base_o;
  u16x8 gc0 = *(const u16x8*)(g0row);
  u16x8 gc1 = *(const u16x8*)(g0row + 8);
  u16x8 gc2 = *(const u16x8*)(g0row + 16);
  u16x8 gc3 = *(const u16x8*)(g0row + 24);

  // ---- fold previous stage (thread per point)
  if (tid < 16) {
    int p = p0 + tid;
    float xc0 = a.x_cur[p * 3], xc1 = a.x_cur[p * 3 + 1], xc2 = a.x_cur[p * 3 + 2];
    float o0 = xc0, o1 = xc1, o2 = xc2;
    if (a.mode_prev >= 0) {
      float tp = a.ts_prev * dt;
      float dx[3], gate[3];
      #pragma unroll
      for (int r = 0; r < 3; ++r) {
        float fr = a.accum6[(size_t)p * 6 + r];
        gate[r] = sigf(a.G3[p * 3 + r] + tp * a.Wg3[r * 65]);
        float bias = a.B3[p * 3 + r] + tp * a.Wb3[r * 65];
        dx[r] = fmaf(fr + a.b3[r], gate[r], bias);
      }
      float klv = -(a.accum6[(size_t)p * 6 + 3] * gate[0] +
                    a.accum6[(size_t)p * 6 + 4] * gate[1] +
                    a.accum6[(size_t)p * 6 + 5] * gate[2]);
      int m = a.mode_prev;
      if (m == 0) {
        o0 = xc0 + 0.5f * dt * dx[0]; o1 = xc1 + 0.5f * dt * dx[1]; o2 = xc2 + 0.5f * dt * dx[2];
        a.kx[p * 3] = dx[0]; a.kx[p * 3 + 1] = dx[1]; a.kx[p * 3 + 2] = dx[2];
        a.kl[p] = klv;
      } else if (m == 1) {
        o0 = xc0 + 0.5f * dt * dx[0]; o1 = xc1 + 0.5f * dt * dx[1]; o2 = xc2 + 0.5f * dt * dx[2];
        a.kx[p * 3] += 2.f * dx[0]; a.kx[p * 3 + 1] += 2.f * dx[1]; a.kx[p * 3 + 2] += 2.f * dx[2];
        a.kl[p] += 2.f * klv;
      } else if (m == 2) {
        o0 = xc0 + dt * dx[0]; o1 = xc1 + dt * dx[1]; o2 = xc2 + dt * dx[2];
        a.kx[p * 3] += 2.f * dx[0]; a.kx[p * 3 + 1] += 2.f * dx[1]; a.kx[p * 3 + 2] += 2.f * dx[2];
        a.kl[p] += 2.f * klv;
      } else {
        float sc = dt * (1.f / 6.f);
        o0 = xc0 + sc * (a.kx[p * 3] + dx[0]);
        o1 = xc1 + sc * (a.kx[p * 3 + 1] + dx[1]);
        o2 = xc2 + sc * (a.kx[p * 3 + 2] + dx[2]);
        a.x_cur[p * 3] = o0; a.x_cur[p * 3 + 1] = o1; a.x_cur[p * 3 + 2] = o2;
        a.lp_state[p] += sc * (a.kl[p] + klv);
      }
    }
    xe[tid][0] = o0; xe[tid][1] = o1; xe[tid][2] = o2;
  }
  __syncthreads();

  float t = a.ts_cur * dt;

  // ---- layer0: 32 threads per point, 16 cols each -> H1 (fp8) in LDS
  // streams 1..3 scaled by TS to stay in e4m3 normal range
  {
    float x0 = xe[pl0][0], x1 = xe[pl0][1], x2 = xe[pl0][2];
    u16x8 gcv[4] = {gc0, gc1, gc2, gc3};
    #pragma unroll
    for (int cc = 0; cc < 4; ++cc) {
      u16x8 v = gcv[cc];
      unsigned oh = 0, od0 = 0, od1 = 0, od2 = 0;
      #pragma unroll
      for (int k = 0; k < 4; ++k) {
        int o = base_o + cc * 4 + k;
        f32x4 e = *(const f32x4*)(a.E0 + (size_t)o * 8);
        f32x2 e2 = *(const f32x2*)(a.E0 + (size_t)o * 8 + 4);
        float u = fmaf(e[0], x0, fmaf(e[1], x1, e[2] * x2)) + e[3];
        float gate = sigf(bf2f(v[2 * k]) + t * e2[0]);
        float bias = bf2f(v[2 * k + 1]) + t * e2[1];
        float z = fmaf(u, gate, bias);
        float h = fast_tanh(z);
        float wm = (1.f - h * h) * gate * TS;
        oh  |= ((unsigned)f2f8(h)) << (8 * k);
        od0 |= ((unsigned)f2f8(wm * e[0])) << (8 * k);
        od1 |= ((unsigned)f2f8(wm * e[1])) << (8 * k);
        od2 |= ((unsigned)f2f8(wm * e[2])) << (8 * k);
      }
      size_t hb = (size_t)(pl0 * 4) * HSTRB + base_o + cc * 4;
      *(unsigned*)(Hs + hb) = oh;
      *(unsigned*)(Hs + hb + HSTRB) = od0;
      *(unsigned*)(Hs + hb + 2 * HSTRB) = od1;
      *(unsigned*)(Hs + hb + 3 * HSTRB) = od2;
    }
  }

  // ---- prefetch epilogue-1 gate dwords (hidden behind GEMM1)
  unsigned g1v[4][4];
  #pragma unroll
  for (int j = 0; j < 4; ++j)
    #pragma unroll
    for (int i = 0; i < 4; ++i) {
      int n = n0 + j * 16 + lr;
      int p = p0 + i * 4 + quad;
      g1v[j][i] = *(const unsigned*)(a.GBi1 + (size_t)p * 1024 + 2 * n);
    }
  __syncthreads();

  // ---- layer1 GEMM (64x64 tile per wave, fp8)
  f32x4 acc[4][4];
  #pragma unroll
  for (int i = 0; i < 4; ++i)
    #pragma unroll
    for (int j = 0; j < 4; ++j)
      #pragma unroll
      for (int r = 0; r < 4; ++r) acc[i][j][r] = 0.f;
  {
    const u8* wp = a.W1f8 + ((size_t)(n0 + lr) * 512 + quad * 8);
    #pragma unroll 2
    for (int k0 = 0; k0 < 512; k0 += 32) {
      i64 bf[4], af[4];
      #pragma unroll
      for (int j = 0; j < 4; ++j)
        bf[j] = *(const i64*)(wp + (size_t)j * 16 * 512 + k0);
      #pragma unroll
      for (int i = 0; i < 4; ++i)
        af[i] = *(const i64*)(Hs + (size_t)(i * 16 + lr) * HSTRB + k0 + quad * 8);
      #pragma unroll
      for (int i = 0; i < 4; ++i)
        #pragma unroll
        for (int j = 0; j < 4; ++j)
          acc[i][j] = __builtin_amdgcn_mfma_f32_16x16x32_fp8_fp8(af[i], bf[j], acc[i][j], 0, 0, 0);
    }
  }
  __syncthreads();   // all H1 reads done

  // ---- epilogue1 -> H2 (fp8) in same LDS (FULLY unrolled)
  #pragma unroll
  for (int j = 0; j < 4; ++j) {
    int n = n0 + j * 16 + lr;
    f32x4 e1 = *(const f32x4*)(a.E1 + (size_t)n * 4);
    #pragma unroll
    for (int i = 0; i < 4; ++i) {
      unsigned d = g1v[j][i];
      float gate = sigf(bf2f((u16)(d & 0xffffu)) + t * e1[1]);
      float bias = bf2f((u16)(d >> 16)) + t * e1[2];
      f32x4 u = acc[i][j];
      float z = fmaf(u[0] + e1[0], gate, bias);
      float h = fast_tanh(z);
      float wmf = (1.f - h * h) * gate;
      int row = i * 16 + quad * 4;
      Hs[(size_t)row * HSTRB + n] = f2f8(h);
      Hs[(size_t)(row + 1) * HSTRB + n] = f2f8(u[1] * wmf);
      Hs[(size_t)(row + 2) * HSTRB + n] = f2f8(u[2] * wmf);
      Hs[(size_t)(row + 3) * HSTRB + n] = f2f8(u[3] * wmf);
    }
  }

  // ---- prefetch epilogue-2 gate dwords (hidden behind GEMM2)
  unsigned g2v[4][4];
  #pragma unroll
  for (int j = 0; j < 4; ++j)
    #pragma unroll
    for (int i = 0; i < 4; ++i) {
      int n = n0 + j * 16 + lr;
      int p = p0 + i * 4 + quad;
      g2v[j][i] = *(const unsigned*)(a.GBi2 + (size_t)p * 1024 + 2 * n);
    }
  __syncthreads();

  // ---- layer2 GEMM (fp8)
  #pragma unroll
  for (int i = 0; i < 4; ++i)
    #pragma unroll
    for (int j = 0; j < 4; ++j)
      #pragma unroll
      for (int r = 0; r < 4; ++r) acc[i][j][r] = 0.f;
  {
    const u8* wp = a.W2f8 + ((size_t)(n0 + lr) * 512 + quad * 8);
    #pragma unroll 2
    for (int k0 = 0; k0 < 512; k0 += 32) {
      i64 bf[4], af[4];
      #pragma unroll
      for (int j = 0; j < 4; ++j)
        bf[j] = *(const i64*)(wp + (size_t)j * 16 * 512 + k0);
      #pragma unroll
      for (int i = 0; i < 4; ++i)
        af[i] = *(const i64*)(Hs + (size_t)(i * 16 + lr) * HSTRB + k0 + quad * 8);
      #pragma unroll
      for (int i = 0; i < 4; ++i)
        #pragma unroll
        for (int j = 0; j < 4; ++j)
          acc[i][j] = __builtin_amdgcn_mfma_f32_16x16x32_fp8_fp8(af[i], bf[j], acc[i][j], 0, 0, 0);
    }
  }

  // ---- epilogue2: gate/tanh + project onto W3 -> 6 partials per point
  #pragma unroll
  for (int i = 0; i < 4; ++i) {
    float v0 = 0.f, v1 = 0.f, v2 = 0.f, v3 = 0.f, v4 = 0.f, v5 = 0.f;
    int pl = i * 4 + quad;
    #pragma unroll
    for (int j = 0; j < 4; ++j) {
      int n = n0 + j * 16 + lr;
      f32x4 ea = *(const f32x4*)(a.E2 + (size_t)n * 8);
      f32x2 eb = *(const f32x2*)(a.E2 + (size_t)n * 8 + 4);
      unsigned d = g2v[j][i];
      float gate = sigf(bf2f((u16)(d & 0xffffu)) + t * ea[1]);
      float bias = bf2f((u16)(d >> 16)) + t * ea[2];
      f32x4 u = acc[i][j];
      float z = fmaf(u[0] + ea[0], gate, bias);
      float h = fast_tanh(z);
      float wmf = (1.f - h * h) * gate;
      float w30 = ea[3], w31 = eb[0], w32 = eb[1];
      v0 = fmaf(h, w30, v0);
      v1 = fmaf(h, w31, v1);
      v2 = fmaf(h, w32, v2);
      v3 = fmaf(u[1] * wmf, w30, v3);
      v4 = fmaf(u[2] * wmf, w31, v4);
      v5 = fmaf(u[3] * wmf, w32, v5);
    }
    #pragma unroll
    for (int mask = 1; mask <= 8; mask <<= 1) {
      v0 += __shfl_xor(v0, mask);
      v1 += __shfl_xor(v1, mask);
      v2 += __shfl_xor(v2, mask);
      v3 += __shfl_xor(v3, mask);
      v4 += __shfl_xor(v4, mask);
      v5 += __shfl_xor(v5, mask);
    }
    // tangent streams carry TS scale through both GEMMs -> undo here
    float val = (lr == 0) ? v0 : (lr == 1) ? v1 : (lr == 2) ? v2
              : (lr == 3) ? v3 * (1.f / TS) : (lr == 4) ? v4 * (1.f / TS)
              : v5 * (1.f / TS);
    if (lr < 6) part[w][pl][lr] = val;
  }
  __syncthreads();

  if (tid < 96) {
    int pt = tid / 6, d = tid - pt * 6;
    float sum = 0.f;
    #pragma unroll
    for (int ww = 0; ww < 8; ++ww) sum += part[ww][pt][d];
    a.accum6[(size_t)(p0 + pt) * 6 + d] = sum;
  }
}

// ---------------------------------------------------------------- finalize
struct FinArgs {
  const float* sqrtT;
  const float* accum6;
  const float *G3, *B3, *Wg3, *Wb3, *b3;
  float *x_cur, *kx, *kl, *lp_state;
  const float *m2, *v2, *lg2, *be2;
  float* out_x;
};
__global__ void finalize_kernel(FinArgs a) {
  int p = blockIdx.x * 256 + threadIdx.x;
  if (p >= PTS) return;
  float s0 = a.sqrtT[0];
  float dt = s0 * s0 * (1.f / 3.f);
  float tp = 3.f * dt;
  float dx[3], gate[3];
  #pragma unroll
  for (int r = 0; r < 3; ++r) {
    float fr = a.accum6[(size_t)p * 6 + r];
    gate[r] = sigf(a.G3[p * 3 + r] + tp * a.Wg3[r * 65]);
    float bias = a.B3[p * 3 + r] + tp * a.Wb3[r * 65];
    dx[r] = fmaf(fr + a.b3[r], gate[r], bias);
  }
  float klv = -(a.accum6[(size_t)p * 6 + 3] * gate[0] +
                a.accum6[(size_t)p * 6 + 4] * gate[1] +
                a.accum6[(size_t)p * 6 + 5] * gate[2]);
  float sc = dt * (1.f / 6.f);
  #pragma unroll
  for (int r = 0; r < 3; ++r) {
    float xf = a.x_cur[p * 3 + r] + sc * (a.kx[p * 3 + r] + dx[r]);
    a.out_x[p * 3 + r] = (xf - a.m2[r]) * __expf(a.lg2[r]) * rsqrtf(a.v2[r] + BN_EPS) + a.be2[r];
  }
  a.lp_state[p] += sc * (a.kl[p] + klv);
}

__global__ void finish_lp(const float* __restrict__ lp_state,
                          const float* __restrict__ v1, const float* __restrict__ lg1,
                          const float* __restrict__ v2, const float* __restrict__ lg2,
                          float* __restrict__ out) {
  int b = blockIdx.x, tid = threadIdx.x;
  float s = 0.f;
  for (int n = tid; n < 2048; n += 256) s += lp_state[b * 2048 + n];
  __shared__ float red[256];
  red[tid] = s;
  __syncthreads();
  for (int w = 128; w > 0; w >>= 1) {
    if (tid < w) red[tid] += red[tid + w];
    __syncthreads();
  }
  if (tid == 0) {
    float ld = 0.f;
    for (int d = 0; d < 3; ++d) {
      ld += lg1[d] - 0.5f * logf(v1[d] + BN_EPS);
      ld += lg2[d] - 0.5f * logf(v2[d] + BN_EPS);
    }
    out[b] = red[0] - 2048.f * ld;
  }
}

// ---------------------------------------------------------------- launch
extern "C" void kernel_launch(void* const* d_in, const int* in_sizes, int n_in,
                              void* d_out, int out_size, void* d_ws, size_t ws_size,
                              hipStream_t stream) {
  const float* x        = (const float*)d_in[0];
  const float* c        = (const float*)d_in[1];
  const float* bn1_mean = (const float*)d_in[2];
  const float* bn1_var  = (const float*)d_in[3];
  const float* bn1_lg   = (const float*)d_in[4];
  const float* bn1_beta = (const float*)d_in[5];
  const float* bn2_mean = (const float*)d_in[6];
  const float* bn2_var  = (const float*)d_in[7];
  const float* bn2_lg   = (const float*)d_in[8];
  const float* bn2_beta = (const float*)d_in[9];
  const float* sqrtT    = (const float*)d_in[10];
  const float* W0  = (const float*)d_in[11];
  const float* b0  = (const float*)d_in[12];
  const float* Wg0 = (const float*)d_in[13];
  const float* bg0 = (const float*)d_in[14];
  const float* Wb0 = (const float*)d_in[15];
  const float* W1  = (const float*)d_in[16];
  const float* b1  = (const float*)d_in[17];
  const float* Wg1 = (const float*)d_in[18];
  const float* bg1 = (const float*)d_in[19];
  const float* Wb1 = (const float*)d_in[20];
  const float* W2  = (const float*)d_in[21];
  const float* b2  = (const float*)d_in[22];
  const float* Wg2 = (const float*)d_in[23];
  const float* bg2 = (const float*)d_in[24];
  const float* Wb2 = (const float*)d_in[25];
  const float* W3  = (const float*)d_in[26];
  const float* b3  = (const float*)d_in[27];
  const float* Wg3 = (const float*)d_in[28];
  const float* bg3 = (const float*)d_in[29];
  const float* Wb3 = (const float*)d_in[30];

  char* base = (char*)d_ws;
  size_t off = 0;
  auto alloc = [&](size_t bytes) -> void* {
    void* pp = base + off;
    off += (bytes + 255) & ~(size_t)255;
    return pp;
  };
  u8* W1f8 = (u8*)alloc((size_t)512 * 512);
  u8* W2f8 = (u8*)alloc((size_t)512 * 512);
  u16* cb  = (u16*)alloc((size_t)PTS * 64 * 2);
  u16* Wpack = (u16*)alloc((size_t)6 * 512 * 64 * 2);
  float* bias_pack = (float*)alloc((size_t)3072 * 4);
  u16* GBi = (u16*)alloc((size_t)3 * PTS * 1024 * 2);
  const size_t SZi = (size_t)PTS * 1024;
  u16* GBi0 = GBi;
  u16* GBi1 = GBi + SZi;
  u16* GBi2 = GBi + 2 * SZi;
  float* G3f = (float*)alloc((size_t)PTS * 3 * 4);
  float* B3f = (float*)alloc((size_t)PTS * 3 * 4);
  float* E0 = (float*)alloc((size_t)512 * 8 * 4);
  float* E1 = (float*)alloc((size_t)512 * 4 * 4);
  float* E2 = (float*)alloc((size_t)512 * 8 * 4);
  float* accum6   = (float*)alloc((size_t)PTS * 6 * 4);
  float* x_cur    = (float*)alloc((size_t)PTS * 3 * 4);
  float* kx       = (float*)alloc((size_t)PTS * 3 * 4);
  float* kl       = (float*)alloc((size_t)PTS * 4);
  float* lp_state = (float*)alloc((size_t)PTS * 4);
  (void)ws_size; (void)in_sizes; (void)n_in; (void)out_size;

  PrepArgs pa{W1, W2, W1f8, W2f8, c, cb, Wg0, Wg1, Wg2, Wb0, Wb1, Wb2,
              bg0, bg1, bg2, Wpack, bias_pack, x, bn1_mean, bn1_var,
              bn1_lg, bn1_beta, x_cur, lp_state, Wg3, bg3, Wb3, G3f, B3f,
              W0, b0, b1, b2, W3, E0, E1, E2};
  prep_kernel<<<2048, 256, 0, stream>>>(pa);

  GatesGemmArgs gg{cb, Wpack, bias_pack, GBi};
  gates_gemm<<<dim3(64, 24), 256, 0, stream>>>(gg);

  auto ts_of = [](int s) -> float {
    static const float frac[4] = {0.f, 0.5f, 0.5f, 1.f};
    return (float)(s >> 2) + frac[s & 3];
  };

  for (int s = 0; s < 12; ++s) {
    StageArgs sa{sqrtT, (s == 0) ? 0.f : ts_of(s - 1), ts_of(s),
                 (s == 0) ? -1 : ((s - 1) & 3), accum6,
                 G3f, B3f, Wg3, Wb3, b3, x_cur, kx, kl, lp_state,
                 GBi0, GBi1, GBi2, E0, E1, E2, W1f8, W2f8};
    stage_kernel<<<PTS / 16, 512, 0, stream>>>(sa);
  }

  FinArgs fa{sqrtT, accum6, G3f, B3f, Wg3, Wb3, b3, x_cur, kx, kl,
             lp_state, bn2_mean, bn2_var, bn2_lg, bn2_beta, (float*)d_out};
  finalize_kernel<<<32, 256, 0, stream>>>(fa);
  finish_lp<<<4, 256, 0, stream>>>(lp_state, bn1_var, bn1_lg, bn2_var, bn2_lg,
                                   (float*)d_out + PTS * 3);
}